// Round 4
// baseline (785.738 us; speedup 1.0000x reference)
//
#include <hip/hip_runtime.h>
#include <hip/hip_bf16.h>

#define N_NODESC 50000
#define N_EDGESC 1600000
#define SDIM 64
#define VDIM 32
#define HID 96
#define IN_DIMC 163

#define GRID_E 2500
#define TPB_E 10           // tiles per block (25000 tiles / 2500 blocks)
#define NXCD 8
#define XQ (GRID_E / NXCD) // 312
#define XR (GRID_E % NXCD) // 4

typedef float f32x4 __attribute__((ext_vector_type(4)));
typedef short s16x8 __attribute__((ext_vector_type(8)));

__device__ __forceinline__ float bf2f(__hip_bfloat16 x) { return __bfloat162float(x); }
__device__ __forceinline__ __hip_bfloat16 f2bf(float x) { return __float2bfloat16(x); }
__device__ __forceinline__ float bfbits2f(short b) {
    unsigned u = ((unsigned)(unsigned short)b) << 16;
    return __builtin_bit_cast(float, u);
}
__device__ __forceinline__ short f2bfbits(float x) {
    __hip_bfloat16 h = __float2bfloat16(x);
    return *(const short*)&h;
}

// ---------------------------------------------------------------------------
// Detect whether edge_index arrived as int64 (odd int32 words all zero) or int32.
__global__ void detect_kernel(const int* ei, int* flag) {
    if (blockIdx.x == 0 && threadIdx.x == 0) {
        int z = 1;
        for (int k = 0; k < 64; ++k) {
            if (ei[2 * k + 1] != 0) { z = 0; break; }
        }
        *flag = z;  // 1 -> int64 layout
    }
}

// ---------------------------------------------------------------------------
// Fused one-shot prep for the sorted tier.
__global__ void fused_init(const float* __restrict__ hs, const float* __restrict__ hv,
                           float* __restrict__ out, int* __restrict__ counts,
                           const float* __restrict__ W1, const float* __restrict__ W2,
                           __hip_bfloat16* __restrict__ SrcRec,
                           __hip_bfloat16* __restrict__ WbT2,
                           __hip_bfloat16* __restrict__ W1cT,
                           __hip_bfloat16* __restrict__ W2Tb,
                           const int* __restrict__ ei, int* __restrict__ flag) {
    int i = blockIdx.x * blockDim.x + threadIdx.x;
    if (i < N_NODESC * (SDIM + VDIM))
        out[i] = (i < N_NODESC * SDIM) ? hs[i] : hv[i - N_NODESC * SDIM];
    if (i < N_NODESC) counts[i] = 0;
    if (i < N_NODESC * VDIM) {
        int n = i >> 5, f = i & 31;
        SrcRec[n * 128 + 96 + f] = f2bf(hv[i]);
    }
    if (i < 192 * 64) {
        int n = i >> 6, k = i & 63;
        float val = (n < 96) ? W1[k * HID + n] : W1[(64 + k) * HID + (n - 96)];
        WbT2[i] = f2bf(val);
    }
    if (i < 96 * 32) {
        int n = i >> 5, k = i & 31;
        W1cT[i] = f2bf(W1[(128 + k) * HID + n]);
    }
    if (i < 96 * 96) {
        int n = i / 96, k = i - (i / 96) * 96;
        W2Tb[i] = f2bf(W2[k * HID + n]);
    }
    if (i == 0) {
        int z = 1;
        for (int kk = 0; kk < 64; ++kk) if (ei[2 * kk + 1] != 0) { z = 0; break; }
        *flag = z;
    }
}

// ---------------------------------------------------------------------------
// MFMA node precompute (K=64): [P|Q] = hs_bf16 @ [W1a|W1b]; P (+b1) ->
// SrcRec[n][0:96), Q -> Qt[n][:]. Output staged in LDS then stored COALESCED
// (16B chunks) — the old direct D-layout store was 2B at 256B stride (~64x
// write amplification).
__global__ __launch_bounds__(256, 2) void node_precompute_mfma(
    const float* __restrict__ hs, const __hip_bfloat16* __restrict__ WbT2,
    const float* __restrict__ b1,
    __hip_bfloat16* __restrict__ SrcRec, __hip_bfloat16* __restrict__ Qt) {
    __shared__ __hip_bfloat16 sA[64][72];
    __shared__ __hip_bfloat16 sOut[64][200];  // 192 used
    const int t = threadIdx.x;
    const int lane = t & 63;
    const int w = t >> 6;
    const int m16 = lane & 15;
    const int q = lane >> 4;
    const int nb = blockIdx.x * 64;

    for (int idx = t; idx < 64 * 64; idx += 256) {
        int node = idx >> 6, f = idx & 63;
        int g = nb + node;
        sA[node][f] = f2bf(g < N_NODESC ? hs[g * SDIM + f] : 0.f);
    }
    __syncthreads();

    // wave w covers output units n_out = w*48 + nt*16 + m16, nt = 0..2
    s16x8 bfr[3][2];
    float b1v[3];
    for (int nt = 0; nt < 3; ++nt) {
        int n_out = w * 48 + nt * 16 + m16;
        for (int kt = 0; kt < 2; ++kt)
            bfr[nt][kt] = *(const s16x8*)&WbT2[n_out * 64 + kt * 32 + q * 8];
        b1v[nt] = (n_out < 96) ? b1[n_out] : 0.f;
    }

    for (int ms = 0; ms < 4; ++ms) {
        s16x8 afr[2];
        for (int kt = 0; kt < 2; ++kt)
            afr[kt] = *(const s16x8*)&sA[ms * 16 + m16][kt * 32 + q * 8];
        f32x4 acc[3];
        for (int nt = 0; nt < 3; ++nt) acc[nt] = (f32x4){0.f, 0.f, 0.f, 0.f};
        for (int nt = 0; nt < 3; ++nt)
            for (int kt = 0; kt < 2; ++kt)
                acc[nt] = __builtin_amdgcn_mfma_f32_16x16x32_bf16(
                    afr[kt], bfr[nt][kt], acc[nt], 0, 0, 0);
        for (int nt = 0; nt < 3; ++nt) {
            int n_out = w * 48 + nt * 16 + m16;
            for (int r = 0; r < 4; ++r)
                sOut[ms * 16 + q * 4 + r][n_out] = f2bf(acc[nt][r] + b1v[nt]);
        }
    }
    __syncthreads();

    // Coalesced stores: P chunks then Q chunks (12 x 16B per node each).
    for (int idx = t; idx < 64 * 12; idx += 256) {
        int node = idx / 12, ch = idx - (idx / 12) * 12;
        int g = nb + node;
        if (g < N_NODESC)
            *(s16x8*)&SrcRec[g * 128 + ch * 8] = *(const s16x8*)&sOut[node][ch * 8];
    }
    for (int idx = t; idx < 64 * 12; idx += 256) {
        int node = idx / 12, ch = idx - (idx / 12) * 12;
        int g = nb + node;
        if (g < N_NODESC)
            *(s16x8*)&Qt[g * 96 + ch * 8] = *(const s16x8*)&sOut[node][96 + ch * 8];
    }
}

// ---------------------------------------------------------------------------
// Counting sort by dst.
__global__ __launch_bounds__(256) void hist_kernel(
    const int* __restrict__ ei, const int* __restrict__ flag64,
    int* __restrict__ counts) {
    int e = blockIdx.x * blockDim.x + threadIdx.x;
    if (e >= N_EDGESC) return;
    int dN;
    if (*flag64) dN = (int)((const long long*)ei)[N_EDGESC + e];
    else dN = ei[N_EDGESC + e];
    atomicAdd(&counts[dN], 1);
}

__global__ __launch_bounds__(1024) void scan_kernel(
    const int* __restrict__ counts, int* __restrict__ cur) {
    __shared__ int part[1024];
    const int t = threadIdx.x;
    const int CH = (N_NODESC + 1023) / 1024;  // 49
    int lo = t * CH;
    int hi = lo + CH; if (hi > N_NODESC) hi = N_NODESC;
    int s = 0;
    for (int i = lo; i < hi; ++i) s += counts[i];
    part[t] = s;
    __syncthreads();
    for (int d = 1; d < 1024; d <<= 1) {
        int v = (t >= d) ? part[t - d] : 0;
        __syncthreads();
        part[t] += v;
        __syncthreads();
    }
    int run = (t == 0) ? 0 : part[t - 1];
    for (int i = lo; i < hi; ++i) {
        int c = counts[i];
        cur[i] = run;
        run += c;
    }
}

__global__ __launch_bounds__(256) void scatter_kernel(
    const int* __restrict__ ei, const int* __restrict__ flag64,
    int* __restrict__ cur, int2* __restrict__ edges) {
    int e = blockIdx.x * blockDim.x + threadIdx.x;
    if (e >= N_EDGESC) return;
    int sN, dN;
    if (*flag64) {
        const long long* e64 = (const long long*)ei;
        sN = (int)e64[e]; dN = (int)e64[N_EDGESC + e];
    } else { sN = ei[e]; dN = ei[N_EDGESC + e]; }
    int p = atomicAdd(&cur[dN], 1);
    edges[p] = make_int2(sN, dN);
}

// ---------------------------------------------------------------------------
// Main edge kernel (dst-sorted, chunked+XCD-swizzled tiles).
// Per tile (4 barriers):
//  [B1] fused staging: thread t -> (edge t>>2, quad t&3); redundant per-edge
//       geo/sincos in regs; hv 16B gather + rotate -> hV (own-wave rows);
//       K=32 MFMA (barrier-free, own-wave rows) -> s_vf bf16.
//  [B2] phase 1b (block-wide): 3 independent (P,Q) 16B gather pairs/thread
//       + s_vf + geo -> silu -> hA.
//  [B3] layer-2 MFMA -> msg overwrites s_vf (barrier-separated).
//  [B4] per-wave segment ballot + block-wide segment-reduce, one atomic per
//       (segment, unit).
__global__ __launch_bounds__(256, 4) void edge_kernel_sorted(
    const int2* __restrict__ edges,
    const float* __restrict__ pos, const float* __restrict__ ori,
    const float* __restrict__ W1, const __hip_bfloat16* __restrict__ W2Tb,
    const float* __restrict__ b2,
    const __hip_bfloat16* __restrict__ SrcRec, const __hip_bfloat16* __restrict__ Qt,
    const __hip_bfloat16* __restrict__ W1cT,
    float* __restrict__ out) {
    __shared__ int s_src[64], s_dst[64];
    __shared__ float s_d[64], s_cg[64], s_sg[64];
    __shared__ float s_w1d[3][HID];
    __shared__ alignas(16) __hip_bfloat16 hV[64][40];    // rotated hv (32 used)
    __shared__ alignas(16) __hip_bfloat16 s_vf[64][104]; // vec contrib; reused as msg
    __shared__ alignas(16) __hip_bfloat16 hA[64][104];   // silu(layer1)
    __shared__ int s_segstart[66];

    const int t = threadIdx.x;
    const int lane = t & 63;
    const int w = t >> 6;        // wave id 0..3
    const int m16 = lane & 15;
    const int q = lane >> 4;

    for (int idx = t; idx < 3 * HID; idx += 256) {
        int r = idx / HID, j = idx - r * HID;
        s_w1d[r][j] = W1[(160 + r) * HID + j];
    }

    // Hoisted B fragments: W2 (18 frags) and W1c (6 frags, K=32).
    s16x8 bfr[6][3], bfrC[6];
    for (int nt = 0; nt < 6; ++nt) {
        for (int kt = 0; kt < 3; ++kt)
            bfr[nt][kt] = *(const s16x8*)&W2Tb[(nt * 16 + m16) * 96 + kt * 32 + q * 8];
        bfrC[nt] = *(const s16x8*)&W1cT[(nt * 16 + m16) * 32 + q * 8];
    }
    float b2v[6];
    for (int nt = 0; nt < 6; ++nt) b2v[nt] = b2[nt * 16 + m16];

    // Chunked, XCD-swizzled tile range.
    int b = blockIdx.x;
    int xcd = b & 7, bi = b >> 3;
    int c = (xcd < XR) ? (xcd * (XQ + 1) + bi)
                       : (XR * (XQ + 1) + (xcd - XR) * XQ + bi);
    const int tile0 = c * TPB_E;

    for (int tl = 0; tl < TPB_E; ++tl) {
        const int tile = tile0 + tl;
        __syncthreads();  // [B1] prior tile fully consumed; LDS reusable

        // --- fused staging + vrot + vec-MFMA (all 256 threads) ---
        {
            const int el = t >> 2;       // = w*16 + (lane>>2)
            const int quad = t & 3;
            int2 ed = edges[tile * 64 + el];
            int sN = ed.x, dN = ed.y;
            float ca, sa, cb, sb;
            __sincosf(2.0f * ori[dN], &sa, &ca);
            __sincosf(2.0f * ori[sN], &sb, &cb);
            float ce = cb * ca + sb * sa;   // cos(2(beta-alpha))
            float se = sb * ca - cb * sa;   // sin(2(beta-alpha))
            if (quad == 0) {
                s_src[el] = sN; s_dst[el] = dN;
                float dx = pos[2 * sN] - pos[2 * dN];
                float dy = pos[2 * sN + 1] - pos[2 * dN + 1];
                float d2 = dx * dx + dy * dy;
                s_d[el] = sqrtf(d2) + 1e-6f;
                float c2f, s2f;
                if (d2 > 0.f) {
                    float inv = 1.0f / d2;
                    c2f = (dx * dx - dy * dy) * inv;
                    s2f = 2.0f * dx * dy * inv;
                } else { c2f = 1.0f; s2f = 0.0f; }
                s_cg[el] = c2f * ca + s2f * sa;
                s_sg[el] = s2f * ca - c2f * sa;
            }
            // rotate this quad (4 pairs) of hv[src]
            s16x8 hvv = *(const s16x8*)&SrcRec[sN * 128 + 96 + quad * 8];
            s16x8 rv;
            #pragma unroll
            for (int p2 = 0; p2 < 4; ++p2) {
                float x = bfbits2f(hvv[2 * p2]), y = bfbits2f(hvv[2 * p2 + 1]);
                rv[2 * p2]     = f2bfbits(ce * x - se * y);
                rv[2 * p2 + 1] = f2bfbits(se * x + ce * y);
            }
            *(s16x8*)&hV[el][quad * 8] = rv;
        }
        // vec contribution via K=32 MFMA: own-wave hV rows -> s_vf (bf16)
        {
            s16x8 afrV = *(const s16x8*)&hV[w * 16 + m16][q * 8];
            #pragma unroll
            for (int nt = 0; nt < 6; ++nt) {
                f32x4 a1 = __builtin_amdgcn_mfma_f32_16x16x32_bf16(
                    afrV, bfrC[nt], (f32x4){0.f, 0.f, 0.f, 0.f}, 0, 0, 0);
                int u = nt * 16 + m16;
                #pragma unroll
                for (int r = 0; r < 4; ++r)
                    s_vf[w * 16 + q * 4 + r][u] = f2bf(a1[r]);
            }
        }
        __syncthreads();  // [B2] s_vf + s_* visible block-wide

        // --- phase 1b (block-wide): base gathers + s_vf + geo -> silu -> hA ---
        {
            s16x8 Pv[3], Qv[3], Vv[3];
            int e_[3], j_[3];
            #pragma unroll
            for (int i2 = 0; i2 < 3; ++i2) {
                int item = i2 * 256 + t;          // < 768 = 64 edges x 12 jb
                int e = item / 12;
                int j = (item - e * 12) * 8;
                e_[i2] = e; j_[i2] = j;
                Pv[i2] = *(const s16x8*)&SrcRec[s_src[e] * 128 + j];
                Qv[i2] = *(const s16x8*)&Qt[s_dst[e] * 96 + j];
                Vv[i2] = *(const s16x8*)&s_vf[e][j];
            }
            #pragma unroll
            for (int i2 = 0; i2 < 3; ++i2) {
                int e = e_[i2], j = j_[i2];
                float de = s_d[e], cge = s_cg[e], sge = s_sg[e];
                s16x8 hb;
                #pragma unroll
                for (int k2 = 0; k2 < 8; ++k2) {
                    float pre = bfbits2f(Pv[i2][k2]) + bfbits2f(Qv[i2][k2])
                              + bfbits2f(Vv[i2][k2])
                              + de * s_w1d[0][j + k2] + cge * s_w1d[1][j + k2]
                              + sge * s_w1d[2][j + k2];
                    float h = pre / (1.0f + __expf(-pre));  // silu
                    hb[k2] = f2bfbits(h);
                }
                *(s16x8*)&hA[e][j] = hb;
            }
        }
        __syncthreads();  // [B3] hA visible

        // --- layer 2 via MFMA; msg (bf16) overwrites s_vf ---
        {
            s16x8 afr[3];
            #pragma unroll
            for (int kt = 0; kt < 3; ++kt)
                afr[kt] = *(const s16x8*)&hA[w * 16 + m16][kt * 32 + q * 8];
            f32x4 acc[6];
            #pragma unroll
            for (int nt = 0; nt < 6; ++nt) acc[nt] = (f32x4){0.f, 0.f, 0.f, 0.f};
            #pragma unroll
            for (int nt = 0; nt < 6; ++nt)
                #pragma unroll
                for (int kt = 0; kt < 3; ++kt)
                    acc[nt] = __builtin_amdgcn_mfma_f32_16x16x32_bf16(
                        afr[kt], bfr[nt][kt], acc[nt], 0, 0, 0);
            #pragma unroll
            for (int nt = 0; nt < 6; ++nt) {
                int u = nt * 16 + m16;
                float bb = b2v[nt];
                #pragma unroll
                for (int r = 0; r < 4; ++r)
                    s_vf[w * 16 + q * 4 + r][u] = f2bf(acc[nt][r] + bb);
            }
        }
        __syncthreads();  // [B4] msg + s_dst complete

        // --- segments: redundant per-wave ballot (identical writes) ---
        int dl = s_dst[lane];
        int dp = (lane > 0) ? s_dst[lane - 1] : -1;
        bool bnd = (lane > 0) && (dl != dp);
        unsigned long long mask = __ballot(bnd);
        int nseg = (int)__popcll(mask) + 1;
        if (bnd) s_segstart[__popcll(mask & (~0ull >> (63 - lane)))] = lane;
        if (lane == 0) s_segstart[0] = 0;

        // --- reduction: one atomicAdd per (segment, unit) ---
        for (int idx = t; idx < nseg * HID; idx += 256) {
            int sg = idx / HID;
            int u = idx - sg * HID;
            int e0 = s_segstart[sg];
            int e1 = (sg + 1 < nseg) ? s_segstart[sg + 1] : 64;
            float sum = 0.f;
            for (int e = e0; e < e1; ++e) sum += bf2f(s_vf[e][u]);
            int dN = s_dst[e0];
            if (u < SDIM) atomicAdd(&out[dN * SDIM + u], sum);
            else atomicAdd(&out[N_NODESC * SDIM + dN * VDIM + (u - SDIM)], sum);
        }
    }
}

// ---------------------------------------------------------------------------
// Mid-tier: f32 per-node precompute (4 tables) + unsorted atomic-scatter kernel.
__global__ __launch_bounds__(128) void node_precompute(
    const float* __restrict__ hs, const float* __restrict__ hv,
    const float* __restrict__ W1, const float* __restrict__ b1,
    __hip_bfloat16* __restrict__ Pp, __hip_bfloat16* __restrict__ Qt,
    __hip_bfloat16* __restrict__ Ut, __hip_bfloat16* __restrict__ Vt) {
    int n = blockIdx.x;
    __shared__ float s_hs[SDIM];
    __shared__ float s_hv[VDIM];
    int t = threadIdx.x;
    if (t < 64) s_hs[t] = hs[n * SDIM + t];
    else if (t < 96) s_hv[t - 64] = hv[n * VDIM + (t - 64)];
    __syncthreads();
    if (t < HID) {
        float p = b1[t], qq = 0.f, u = 0.f, v = 0.f;
        for (int k = 0; k < 64; ++k) {
            float x = s_hs[k];
            p += x * W1[k * HID + t];
            qq += x * W1[(64 + k) * HID + t];
        }
        for (int pr = 0; pr < 16; ++pr) {
            float x = s_hv[2 * pr], y = s_hv[2 * pr + 1];
            float wa = W1[(128 + 2 * pr) * HID + t];
            float wb = W1[(128 + 2 * pr + 1) * HID + t];
            u += x * wa + y * wb;
            v += x * wb - y * wa;
        }
        Pp[n * HID + t] = f2bf(p);
        Qt[n * HID + t] = f2bf(qq);
        Ut[n * HID + t] = f2bf(u);
        Vt[n * HID + t] = f2bf(v);
    }
}

__global__ void init_out(const float* __restrict__ hs, const float* __restrict__ hv,
                         float* __restrict__ out) {
    int i = blockIdx.x * blockDim.x + threadIdx.x;
    if (i >= N_NODESC * (SDIM + VDIM)) return;
    out[i] = (i < N_NODESC * SDIM) ? hs[i] : hv[i - N_NODESC * SDIM];
}

__global__ __launch_bounds__(256) void edge_kernel(
    const int* __restrict__ ei, const float* __restrict__ pos,
    const float* __restrict__ ori, const float* __restrict__ W1,
    const float* __restrict__ W2, const float* __restrict__ b2,
    const __hip_bfloat16* __restrict__ Pp, const __hip_bfloat16* __restrict__ Qt,
    const __hip_bfloat16* __restrict__ Ut, const __hip_bfloat16* __restrict__ Vt,
    const int* __restrict__ flag64, float* __restrict__ out) {
    __shared__ int s_src[64], s_dst[64];
    __shared__ float s_c[64], s_s[64], s_d[64], s_cg[64], s_sg[64];
    __shared__ float s_w1d[3][HID];
    __shared__ __hip_bfloat16 hA[64][104];
    __shared__ __hip_bfloat16 W2T[HID][104];

    const int t = threadIdx.x;
    const int lane = t & 63;
    const int w = t >> 6;
    const int m16 = lane & 15;
    const int q = lane >> 4;

    for (int idx = t; idx < HID * HID; idx += 256) {
        int k = idx / HID;
        int n = idx - k * HID;
        W2T[n][k] = f2bf(W2[idx]);
    }
    for (int idx = t; idx < 3 * HID; idx += 256) {
        int r = idx / HID, j = idx - r * HID;
        s_w1d[r][j] = W1[(160 + r) * HID + j];
    }
    __syncthreads();

    s16x8 bfr[6][3];
    for (int nt = 0; nt < 6; ++nt)
        for (int kt = 0; kt < 3; ++kt)
            bfr[nt][kt] = *(const s16x8*)&W2T[nt * 16 + m16][kt * 32 + q * 8];
    float b2v[6];
    for (int nt = 0; nt < 6; ++nt) b2v[nt] = b2[nt * 16 + m16];

    const bool i64 = (*flag64 != 0);
    const long long* ei64 = (const long long*)ei;

    for (int tile = blockIdx.x; tile < N_EDGESC / 64; tile += gridDim.x) {
        __syncthreads();

        if (t < 64) {
            int e = tile * 64 + t;
            int sN, dN;
            if (i64) { sN = (int)ei64[e]; dN = (int)ei64[N_EDGESC + e]; }
            else     { sN = ei[e];        dN = ei[N_EDGESC + e]; }
            s_src[t] = sN; s_dst[t] = dN;
            float ca, sa, cb, sb;
            __sincosf(2.0f * ori[dN], &sa, &ca);
            __sincosf(2.0f * ori[sN], &sb, &cb);
            s_c[t] = cb * ca + sb * sa;
            s_s[t] = sb * ca - cb * sa;
            float dx = pos[2 * sN] - pos[2 * dN];
            float dy = pos[2 * sN + 1] - pos[2 * dN + 1];
            float d2 = dx * dx + dy * dy;
            s_d[t] = sqrtf(d2) + 1e-6f;
            float c2f, s2f;
            if (d2 > 0.f) {
                float inv = 1.0f / d2;
                c2f = (dx * dx - dy * dy) * inv;
                s2f = 2.0f * dx * dy * inv;
            } else { c2f = 1.0f; s2f = 0.0f; }
            s_cg[t] = c2f * ca + s2f * sa;
            s_sg[t] = s2f * ca - c2f * sa;
        }
        __syncthreads();

        for (int p = 0; p < 24; ++p) {
            int idx = p * 256 + t;
            int e = idx / HID;
            int j = idx - e * HID;
            int sN = s_src[e], dN = s_dst[e];
            float pre = bf2f(Pp[sN * HID + j]) + bf2f(Qt[dN * HID + j])
                      + s_c[e] * bf2f(Ut[sN * HID + j])
                      + s_s[e] * bf2f(Vt[sN * HID + j])
                      + s_d[e] * s_w1d[0][j] + s_cg[e] * s_w1d[1][j]
                      + s_sg[e] * s_w1d[2][j];
            float h = pre / (1.0f + __expf(-pre));
            hA[e][j] = f2bf(h);
        }
        __syncthreads();

        f32x4 acc[6];
        for (int nt = 0; nt < 6; ++nt) acc[nt] = (f32x4){0.f, 0.f, 0.f, 0.f};
        s16x8 afr[3];
        for (int kt = 0; kt < 3; ++kt)
            afr[kt] = *(const s16x8*)&hA[w * 16 + m16][kt * 32 + q * 8];
        for (int nt = 0; nt < 6; ++nt)
            for (int kt = 0; kt < 3; ++kt)
                acc[nt] = __builtin_amdgcn_mfma_f32_16x16x32_bf16(
                    afr[kt], bfr[nt][kt], acc[nt], 0, 0, 0);

        for (int nt = 0; nt < 6; ++nt) {
            int u = nt * 16 + m16;
            for (int r = 0; r < 4; ++r) {
                int eloc = w * 16 + q * 4 + r;
                int dN = s_dst[eloc];
                float val = acc[nt][r] + b2v[nt];
                if (u < SDIM) atomicAdd(&out[dN * SDIM + u], val);
                else atomicAdd(&out[N_NODESC * SDIM + dN * VDIM + (u - SDIM)], val);
            }
        }
    }
}

// ---------------------------------------------------------------------------
// Fallback (ws too small for tables): fully per-edge, correct but slow.
__global__ __launch_bounds__(192) void edge_fallback(
    const int* __restrict__ ei, const float* __restrict__ hs,
    const float* __restrict__ hv, const float* __restrict__ pos,
    const float* __restrict__ ori, const float* __restrict__ W1,
    const float* __restrict__ b1, const float* __restrict__ W2,
    const float* __restrict__ b2, const int* __restrict__ flag64,
    float* __restrict__ out) {
    __shared__ float s_msg[IN_DIMC];
    __shared__ float s_h[HID];
    int e = blockIdx.x;
    int t = threadIdx.x;
    const bool i64 = (*flag64 != 0);
    int sN, dN;
    if (i64) {
        const long long* e64 = (const long long*)ei;
        sN = (int)e64[e]; dN = (int)e64[N_EDGESC + e];
    } else { sN = ei[e]; dN = ei[N_EDGESC + e]; }

    if (t < IN_DIMC) {
        if (t < 64) s_msg[t] = hs[sN * SDIM + t];
        else if (t < 128) s_msg[t] = hs[dN * SDIM + (t - 64)];
        else {
            float ca, sa, cb, sb;
            __sincosf(2.0f * ori[dN], &sa, &ca);
            __sincosf(2.0f * ori[sN], &sb, &cb);
            float c = cb * ca + sb * sa;
            float s = sb * ca - cb * sa;
            float dx = pos[2 * sN] - pos[2 * dN];
            float dy = pos[2 * sN + 1] - pos[2 * dN + 1];
            float d2 = dx * dx + dy * dy;
            if (t < 160) {
                int pr = (t - 128) >> 1;
                float x = hv[sN * VDIM + 2 * pr], y = hv[sN * VDIM + 2 * pr + 1];
                s_msg[t] = ((t & 1) == 0) ? (c * x - s * y) : (s * x + c * y);
            } else if (t == 160) s_msg[t] = sqrtf(d2) + 1e-6f;
            else {
                float c2f = 1.0f, s2f = 0.0f;
                if (d2 > 0.f) {
                    float inv = 1.0f / d2;
                    c2f = (dx * dx - dy * dy) * inv;
                    s2f = 2.0f * dx * dy * inv;
                }
                s_msg[t] = (t == 161) ? (c2f * ca + s2f * sa) : (s2f * ca - c2f * sa);
            }
        }
    }
    __syncthreads();
    if (t < HID) {
        float a = b1[t];
        for (int k = 0; k < IN_DIMC; ++k) a += s_msg[k] * W1[k * HID + t];
        s_h[t] = a / (1.0f + __expf(-a));
    }
    __syncthreads();
    if (t < HID) {
        float a = b2[t];
        for (int k = 0; k < HID; ++k) a += s_h[k] * W2[k * HID + t];
        if (t < SDIM) atomicAdd(&out[dN * SDIM + t], a);
        else atomicAdd(&out[N_NODESC * SDIM + dN * VDIM + (t - SDIM)], a);
    }
}

// ---------------------------------------------------------------------------
extern "C" void kernel_launch(void* const* d_in, const int* in_sizes, int n_in,
                              void* d_out, int out_size, void* d_ws, size_t ws_size,
                              hipStream_t stream) {
    const float* hs  = (const float*)d_in[0];
    const float* hv  = (const float*)d_in[1];
    const int*   ei  = (const int*)d_in[2];
    const float* pos = (const float*)d_in[3];
    const float* ori = (const float*)d_in[4];
    const float* W1  = (const float*)d_in[5];
    const float* b1  = (const float*)d_in[6];
    const float* W2  = (const float*)d_in[7];
    const float* b2  = (const float*)d_in[8];
    float* out = (float*)d_out;

    // sorted-tier workspace layout (256B-aligned chunks)
    const size_t SREC = (size_t)N_NODESC * 128 * sizeof(__hip_bfloat16);  // 12.8 MB
    const size_t QTB  = (size_t)N_NODESC * 96 * sizeof(__hip_bfloat16);   // 9.6 MB
    const size_t CNT  = ((size_t)N_NODESC * sizeof(int) + 255) & ~255ull; // 200 KB
    const size_t EDG  = (size_t)N_EDGESC * sizeof(int2);                  // 12.8 MB
    const size_t WBT2 = ((size_t)192 * 64 * 2 + 255) & ~255ull;
    const size_t W1CT = ((size_t)96 * 32 * 2 + 255) & ~255ull;
    const size_t W2TS = ((size_t)96 * 96 * 2 + 255) & ~255ull;
    const size_t SORT_WS = SREC + QTB + 2 * CNT + EDG + WBT2 + W1CT + W2TS + 256;

    const size_t TBL = (size_t)N_NODESC * HID * sizeof(__hip_bfloat16);   // 9.6 MB
    const bool big = ws_size >= 4 * TBL + 16;
    const bool srt = ws_size >= SORT_WS;

    if (srt) {
        char* ws = (char*)d_ws;
        __hip_bfloat16* SrcRec = (__hip_bfloat16*)(ws);
        __hip_bfloat16* Qt     = (__hip_bfloat16*)(ws + SREC);
        int* counts            = (int*)(ws + SREC + QTB);
        int* cur               = (int*)(ws + SREC + QTB + CNT);
        int2* edges            = (int2*)(ws + SREC + QTB + 2 * CNT);
        __hip_bfloat16* WbT2   = (__hip_bfloat16*)(ws + SREC + QTB + 2 * CNT + EDG);
        __hip_bfloat16* W1cT   = (__hip_bfloat16*)(ws + SREC + QTB + 2 * CNT + EDG + WBT2);
        __hip_bfloat16* W2Tb   = (__hip_bfloat16*)(ws + SREC + QTB + 2 * CNT + EDG + WBT2 + W1CT);
        int* flag              = (int*)(ws + SREC + QTB + 2 * CNT + EDG + WBT2 + W1CT + W2TS);

        fused_init<<<(N_NODESC * (SDIM + VDIM) + 255) / 256, 256, 0, stream>>>(
            hs, hv, out, counts, W1, W2, SrcRec, WbT2, W1cT, W2Tb, ei, flag);
        hist_kernel<<<N_EDGESC / 256, 256, 0, stream>>>(ei, flag, counts);
        scan_kernel<<<1, 1024, 0, stream>>>(counts, cur);
        scatter_kernel<<<N_EDGESC / 256, 256, 0, stream>>>(ei, flag, cur, edges);
        node_precompute_mfma<<<(N_NODESC + 63) / 64, 256, 0, stream>>>(
            hs, WbT2, b1, SrcRec, Qt);
        edge_kernel_sorted<<<GRID_E, 256, 0, stream>>>(edges, pos, ori, W1, W2Tb, b2,
                                                       SrcRec, Qt, W1cT, out);
    } else if (big) {
        char* ws = (char*)d_ws;
        __hip_bfloat16* Pp = (__hip_bfloat16*)(ws);
        __hip_bfloat16* Qt = (__hip_bfloat16*)(ws + TBL);
        __hip_bfloat16* Ut = (__hip_bfloat16*)(ws + 2 * TBL);
        __hip_bfloat16* Vt = (__hip_bfloat16*)(ws + 3 * TBL);
        int* flag = (int*)(ws + 4 * TBL);
        init_out<<<(N_NODESC * (SDIM + VDIM) + 255) / 256, 256, 0, stream>>>(hs, hv, out);
        detect_kernel<<<1, 64, 0, stream>>>(ei, flag);
        node_precompute<<<N_NODESC, 128, 0, stream>>>(hs, hv, W1, b1, Pp, Qt, Ut, Vt);
        edge_kernel<<<2500, 256, 0, stream>>>(ei, pos, ori, W1, W2, b2,
                                              Pp, Qt, Ut, Vt, flag, out);
    } else {
        int* flag = (int*)d_ws;
        init_out<<<(N_NODESC * (SDIM + VDIM) + 255) / 256, 256, 0, stream>>>(hs, hv, out);
        detect_kernel<<<1, 64, 0, stream>>>(ei, flag);
        edge_fallback<<<N_EDGESC, 192, 0, stream>>>(ei, hs, hv, pos, ori, W1, b1,
                                                    W2, b2, flag, out);
    }
}

// Round 6
// 666.393 us; speedup vs baseline: 1.1791x; 1.1791x over previous
//
#include <hip/hip_runtime.h>
#include <hip/hip_bf16.h>

#define N_NODESC 50000
#define N_EDGESC 1600000
#define SDIM 64
#define VDIM 32
#define HID 96
#define IN_DIMC 163

#define GRID_E 2500
#define TPB_E 10           // tiles per block (25000 tiles / 2500 blocks)
#define NXCD 8
#define XQ (GRID_E / NXCD) // 312
#define XR (GRID_E % NXCD) // 4

typedef float f32x4 __attribute__((ext_vector_type(4)));
typedef short s16x8 __attribute__((ext_vector_type(8)));

__device__ __forceinline__ float bf2f(__hip_bfloat16 x) { return __bfloat162float(x); }
__device__ __forceinline__ __hip_bfloat16 f2bf(float x) { return __float2bfloat16(x); }
__device__ __forceinline__ float bfbits2f(short b) {
    unsigned u = ((unsigned)(unsigned short)b) << 16;
    return __builtin_bit_cast(float, u);
}
__device__ __forceinline__ short f2bfbits(float x) {
    __hip_bfloat16 h = __float2bfloat16(x);
    return *(const short*)&h;
}

// ---------------------------------------------------------------------------
// Detect whether edge_index arrived as int64 (odd int32 words all zero) or int32.
__global__ void detect_kernel(const int* ei, int* flag) {
    if (blockIdx.x == 0 && threadIdx.x == 0) {
        int z = 1;
        for (int k = 0; k < 64; ++k) {
            if (ei[2 * k + 1] != 0) { z = 0; break; }
        }
        *flag = z;  // 1 -> int64 layout
    }
}

__global__ void zero_counts(int* __restrict__ c) {
    int i = blockIdx.x * blockDim.x + threadIdx.x;
    if (i < N_NODESC) c[i] = 0;
}

// ---------------------------------------------------------------------------
// Fused one-shot prep for the sorted tier (also does the dst histogram;
// counts zeroed by zero_counts, flag by detect — both earlier in-stream).
__global__ void fused_init(const float* __restrict__ hs, const float* __restrict__ hv,
                           float* __restrict__ out, int* __restrict__ counts,
                           const float* __restrict__ W1, const float* __restrict__ W2,
                           __hip_bfloat16* __restrict__ SrcRec,
                           __hip_bfloat16* __restrict__ WbT2,
                           __hip_bfloat16* __restrict__ W1cT,
                           __hip_bfloat16* __restrict__ W2Tb,
                           const int* __restrict__ ei, const int* __restrict__ flag64) {
    int i = blockIdx.x * blockDim.x + threadIdx.x;
    if (i < N_NODESC * (SDIM + VDIM))
        out[i] = (i < N_NODESC * SDIM) ? hs[i] : hv[i - N_NODESC * SDIM];
    if (i < N_NODESC * VDIM) {
        int n = i >> 5, f = i & 31;
        SrcRec[n * 128 + 96 + f] = f2bf(hv[i]);
    }
    if (i < 192 * 64) {
        int n = i >> 6, k = i & 63;
        float val = (n < 96) ? W1[k * HID + n] : W1[(64 + k) * HID + (n - 96)];
        WbT2[i] = f2bf(val);
    }
    if (i < 96 * 32) {
        int n = i >> 5, k = i & 31;
        W1cT[i] = f2bf(W1[(128 + k) * HID + n]);
    }
    if (i < 96 * 96) {
        int n = i / 96, k = i - (i / 96) * 96;
        W2Tb[i] = f2bf(W2[k * HID + n]);
    }
    if (i < N_EDGESC) {
        int dN;
        if (*flag64) dN = (int)((const long long*)ei)[N_EDGESC + i];
        else dN = ei[N_EDGESC + i];
        atomicAdd(&counts[dN], 1);
    }
}

// ---------------------------------------------------------------------------
// MFMA node precompute (K=64): [P|Q] = hs_bf16 @ [W1a|W1b]; P (+b1) ->
// SrcRec[n][0:96), Q -> Qt[n][:]. Output staged in LDS, stored coalesced.
__global__ __launch_bounds__(256, 2) void node_precompute_mfma(
    const float* __restrict__ hs, const __hip_bfloat16* __restrict__ WbT2,
    const float* __restrict__ b1,
    __hip_bfloat16* __restrict__ SrcRec, __hip_bfloat16* __restrict__ Qt) {
    __shared__ __hip_bfloat16 sA[64][72];
    __shared__ __hip_bfloat16 sOut[64][200];  // 192 used
    const int t = threadIdx.x;
    const int lane = t & 63;
    const int w = t >> 6;
    const int m16 = lane & 15;
    const int q = lane >> 4;
    const int nb = blockIdx.x * 64;

    for (int idx = t; idx < 64 * 64; idx += 256) {
        int node = idx >> 6, f = idx & 63;
        int g = nb + node;
        sA[node][f] = f2bf(g < N_NODESC ? hs[g * SDIM + f] : 0.f);
    }
    __syncthreads();

    s16x8 bfr[3][2];
    float b1v[3];
    for (int nt = 0; nt < 3; ++nt) {
        int n_out = w * 48 + nt * 16 + m16;
        for (int kt = 0; kt < 2; ++kt)
            bfr[nt][kt] = *(const s16x8*)&WbT2[n_out * 64 + kt * 32 + q * 8];
        b1v[nt] = (n_out < 96) ? b1[n_out] : 0.f;
    }

    for (int ms = 0; ms < 4; ++ms) {
        s16x8 afr[2];
        for (int kt = 0; kt < 2; ++kt)
            afr[kt] = *(const s16x8*)&sA[ms * 16 + m16][kt * 32 + q * 8];
        f32x4 acc[3];
        for (int nt = 0; nt < 3; ++nt) acc[nt] = (f32x4){0.f, 0.f, 0.f, 0.f};
        for (int nt = 0; nt < 3; ++nt)
            for (int kt = 0; kt < 2; ++kt)
                acc[nt] = __builtin_amdgcn_mfma_f32_16x16x32_bf16(
                    afr[kt], bfr[nt][kt], acc[nt], 0, 0, 0);
        for (int nt = 0; nt < 3; ++nt) {
            int n_out = w * 48 + nt * 16 + m16;
            for (int r = 0; r < 4; ++r)
                sOut[ms * 16 + q * 4 + r][n_out] = f2bf(acc[nt][r] + b1v[nt]);
        }
    }
    __syncthreads();

    for (int idx = t; idx < 64 * 12; idx += 256) {
        int node = idx / 12, ch = idx - (idx / 12) * 12;
        int g = nb + node;
        if (g < N_NODESC)
            *(s16x8*)&SrcRec[g * 128 + ch * 8] = *(const s16x8*)&sOut[node][ch * 8];
    }
    for (int idx = t; idx < 64 * 12; idx += 256) {
        int node = idx / 12, ch = idx - (idx / 12) * 12;
        int g = nb + node;
        if (g < N_NODESC)
            *(s16x8*)&Qt[g * 96 + ch * 8] = *(const s16x8*)&sOut[node][96 + ch * 8];
    }
}

// ---------------------------------------------------------------------------
__global__ __launch_bounds__(1024) void scan_kernel(
    const int* __restrict__ counts, int* __restrict__ cur) {
    __shared__ int part[1024];
    const int t = threadIdx.x;
    const int CH = (N_NODESC + 1023) / 1024;  // 49
    int lo = t * CH;
    int hi = lo + CH; if (hi > N_NODESC) hi = N_NODESC;
    int s = 0;
    for (int i = lo; i < hi; ++i) s += counts[i];
    part[t] = s;
    __syncthreads();
    for (int d = 1; d < 1024; d <<= 1) {
        int v = (t >= d) ? part[t - d] : 0;
        __syncthreads();
        part[t] += v;
        __syncthreads();
    }
    int run = (t == 0) ? 0 : part[t - 1];
    for (int i = lo; i < hi; ++i) {
        int c = counts[i];
        cur[i] = run;
        run += c;
    }
}

__global__ __launch_bounds__(256) void scatter_kernel(
    const int* __restrict__ ei, const int* __restrict__ flag64,
    int* __restrict__ cur, int2* __restrict__ edges) {
    int e = blockIdx.x * blockDim.x + threadIdx.x;
    if (e >= N_EDGESC) return;
    int sN, dN;
    if (*flag64) {
        const long long* e64 = (const long long*)ei;
        sN = (int)e64[e]; dN = (int)e64[N_EDGESC + e];
    } else { sN = ei[e]; dN = ei[N_EDGESC + e]; }
    int p = atomicAdd(&cur[dN], 1);
    edges[p] = make_int2(sN, dN);
}

// ---------------------------------------------------------------------------
// Main edge kernel (dst-sorted, chunked+XCD-swizzled, cross-tile prefetch).
// 3 blocks/CU (LDS ~54KB) to stay in the L2-friendly fetch regime (R3 data);
// latency hidden by depth-1/2 register prefetch (issued a full phase ahead;
// drains at __syncthreads but the issue->barrier window covers L2-hit
// latency). W2 B-fragments live fragment-packed in LDS (conflict-free b128).
__global__ __launch_bounds__(256, 3) void edge_kernel_sorted(
    const int2* __restrict__ edges,
    const float* __restrict__ pos, const float* __restrict__ ori,
    const float* __restrict__ W1, const __hip_bfloat16* __restrict__ W2Tb,
    const float* __restrict__ b2,
    const __hip_bfloat16* __restrict__ SrcRec, const __hip_bfloat16* __restrict__ Qt,
    const __hip_bfloat16* __restrict__ W1cT,
    float* __restrict__ out) {
    __shared__ int s_srcM[2][64], s_dstM[2][64];
    __shared__ float s_dM[2][64], s_cgM[2][64], s_sgM[2][64];
    __shared__ float s_w1d[3][HID];
    __shared__ alignas(16) __hip_bfloat16 hV[64][40];     // rotated hv (32 used)
    __shared__ alignas(16) __hip_bfloat16 s_vf[64][104];  // vec contrib / msg
    __shared__ alignas(16) __hip_bfloat16 hA[64][104];    // silu(layer1)
    __shared__ alignas(16) short sW2f[18 * 64 * 8];       // W2 frags, lane-packed
    __shared__ int s_segstart[66];

    const int t = threadIdx.x;
    const int lane = t & 63;
    const int w = t >> 6;        // wave id 0..3
    const int m16 = lane & 15;
    const int q = lane >> 4;
    const int el = t >> 2;       // edge-role: edge index 0..63
    const int quad = t & 3;      // edge-role: quad 0..3

    for (int idx = t; idx < 3 * HID; idx += 256) {
        int r = idx / HID, j = idx - r * HID;
        s_w1d[r][j] = W1[(160 + r) * HID + j];
    }
    // W2 fragments -> LDS, packed by (frag, lane): ds_read_b128 at lane*16B.
    if (w == 0) {
        for (int f = 0; f < 18; ++f) {
            int nt = f / 3, kt = f - (f / 3) * 3;
            *(s16x8*)&sW2f[(f * 64 + lane) * 8] =
                *(const s16x8*)&W2Tb[(nt * 16 + m16) * 96 + kt * 32 + q * 8];
        }
    }
    // W1c fragments in registers (24 VGPR).
    s16x8 bfrC[6];
    #pragma unroll
    for (int nt = 0; nt < 6; ++nt)
        bfrC[nt] = *(const s16x8*)&W1cT[(nt * 16 + m16) * 32 + q * 8];
    float b2v[6];
    #pragma unroll
    for (int nt = 0; nt < 6; ++nt) b2v[nt] = b2[nt * 16 + m16];

    // Chunked, XCD-swizzled tile range.
    int b = blockIdx.x;
    int xcd = b & 7, bi = b >> 3;
    int c = (xcd < XR) ? (xcd * (XQ + 1) + bi)
                       : (XR * (XQ + 1) + (xcd - XR) * XQ + bi);
    const int tile0 = c * TPB_E;

    // ---- prologue: stage tile 0, prefetch tile 1's edge ids ----
    int2 edT1;        // edges for tile tl+1 (edge-role)
    s16x8 hvvT;       // raw hv gather for current tile
    float rcT, rsT;   // rotation coeffs for current tile (edge-role regs)
    {
        int2 edT = edges[tile0 * 64 + el];
        edT1 = edges[(tile0 + (TPB_E > 1 ? 1 : 0)) * 64 + el];
        hvvT = *(const s16x8*)&SrcRec[edT.x * 128 + 96 + quad * 8];
        int sN = edT.x, dN = edT.y;
        float ca, sa, cb, sb;
        __sincosf(2.0f * ori[dN], &sa, &ca);
        __sincosf(2.0f * ori[sN], &sb, &cb);
        rcT = cb * ca + sb * sa;
        rsT = sb * ca - cb * sa;
        if (quad == 0) {
            s_srcM[0][el] = sN; s_dstM[0][el] = dN;
            float dx = pos[2 * sN] - pos[2 * dN];
            float dy = pos[2 * sN + 1] - pos[2 * dN + 1];
            float d2 = dx * dx + dy * dy;
            s_dM[0][el] = sqrtf(d2) + 1e-6f;
            float c2f, s2f;
            if (d2 > 0.f) {
                float inv = 1.0f / d2;
                c2f = (dx * dx - dy * dy) * inv;
                s2f = 2.0f * dx * dy * inv;
            } else { c2f = 1.0f; s2f = 0.0f; }
            s_cgM[0][el] = c2f * ca + s2f * sa;
            s_sgM[0][el] = s2f * ca - c2f * sa;
        }
    }
    __syncthreads();
    // Issue P/Q gathers for tile 0.
    s16x8 pqP[3], pqQ[3];
    #pragma unroll
    for (int i2 = 0; i2 < 3; ++i2) {
        int item = i2 * 256 + t;
        int e = item / 12;
        int j = (item - e * 12) * 8;
        pqP[i2] = *(const s16x8*)&SrcRec[s_srcM[0][e] * 128 + j];
        pqQ[i2] = *(const s16x8*)&Qt[s_dstM[0][e] * 96 + j];
    }

    int cur = 0;
    for (int tl = 0; tl < TPB_E; ++tl) {
        const int nx = cur ^ 1;
        const int tlN2 = (tl + 2 < TPB_E) ? tl + 2 : TPB_E - 1;

        // 1. rotate hv(T) -> hV (own-wave rows)
        {
            s16x8 rv;
            #pragma unroll
            for (int p2 = 0; p2 < 4; ++p2) {
                float x = bfbits2f(hvvT[2 * p2]), y = bfbits2f(hvvT[2 * p2 + 1]);
                rv[2 * p2]     = f2bfbits(rcT * x - rsT * y);
                rv[2 * p2 + 1] = f2bfbits(rsT * x + rcT * y);
            }
            *(s16x8*)&hV[el][quad * 8] = rv;
        }
        // 2/3. prefetch edges(T+2) and hv(T+1) — long-latency, used next iter
        int2 edT2 = edges[(tile0 + tlN2) * 64 + el];
        s16x8 hvvN = *(const s16x8*)&SrcRec[edT1.x * 128 + 96 + quad * 8];
        // 4. vec contribution via K=32 MFMA -> s_vf (own-wave rows)
        {
            s16x8 afrV = *(const s16x8*)&hV[w * 16 + m16][q * 8];
            #pragma unroll
            for (int nt = 0; nt < 6; ++nt) {
                f32x4 a1 = __builtin_amdgcn_mfma_f32_16x16x32_bf16(
                    afrV, bfrC[nt], (f32x4){0.f, 0.f, 0.f, 0.f}, 0, 0, 0);
                int u = nt * 16 + m16;
                #pragma unroll
                for (int r = 0; r < 4; ++r)
                    s_vf[w * 16 + q * 4 + r][u] = f2bf(a1[r]);
            }
        }
        // 5. meta + rotation for T+1 (VALU) -> meta[nx]
        float rcN, rsN;
        {
            int sN = edT1.x, dN = edT1.y;
            float ca, sa, cb, sb;
            __sincosf(2.0f * ori[dN], &sa, &ca);
            __sincosf(2.0f * ori[sN], &sb, &cb);
            rcN = cb * ca + sb * sa;
            rsN = sb * ca - cb * sa;
            if (quad == 0) {
                s_srcM[nx][el] = sN; s_dstM[nx][el] = dN;
                float dx = pos[2 * sN] - pos[2 * dN];
                float dy = pos[2 * sN + 1] - pos[2 * dN + 1];
                float d2 = dx * dx + dy * dy;
                s_dM[nx][el] = sqrtf(d2) + 1e-6f;
                float c2f, s2f;
                if (d2 > 0.f) {
                    float inv = 1.0f / d2;
                    c2f = (dx * dx - dy * dy) * inv;
                    s2f = 2.0f * dx * dy * inv;
                } else { c2f = 1.0f; s2f = 0.0f; }
                s_cgM[nx][el] = c2f * ca + s2f * sa;
                s_sgM[nx][el] = s2f * ca - c2f * sa;
            }
        }
        __syncthreads();  // [B2] s_vf + meta[nx] visible

        // 7. phase-1b: P/Q regs (prefetched) + s_vf + geo -> silu -> hA
        #pragma unroll
        for (int i2 = 0; i2 < 3; ++i2) {
            int item = i2 * 256 + t;
            int e = item / 12;
            int j = (item - e * 12) * 8;
            s16x8 Vv = *(const s16x8*)&s_vf[e][j];
            float de = s_dM[cur][e], cge = s_cgM[cur][e], sge = s_sgM[cur][e];
            s16x8 hb;
            #pragma unroll
            for (int k2 = 0; k2 < 8; ++k2) {
                float pre = bfbits2f(pqP[i2][k2]) + bfbits2f(pqQ[i2][k2])
                          + bfbits2f(Vv[k2])
                          + de * s_w1d[0][j + k2] + cge * s_w1d[1][j + k2]
                          + sge * s_w1d[2][j + k2];
                float h = pre / (1.0f + __expf(-pre));  // silu
                hb[k2] = f2bfbits(h);
            }
            *(s16x8*)&hA[e][j] = hb;
        }
        __syncthreads();  // [B3] hA visible

        // 9. prefetch P/Q for T+1 (indices from meta[nx]); overlaps the MFMA.
        #pragma unroll
        for (int i2 = 0; i2 < 3; ++i2) {
            int item = i2 * 256 + t;
            int e = item / 12;
            int j = (item - e * 12) * 8;
            pqP[i2] = *(const s16x8*)&SrcRec[s_srcM[nx][e] * 128 + j];
            pqQ[i2] = *(const s16x8*)&Qt[s_dstM[nx][e] * 96 + j];
        }
        // 10. layer-2 MFMA (B frags from LDS) -> msg overwrites s_vf
        {
            s16x8 afr[3];
            #pragma unroll
            for (int kt = 0; kt < 3; ++kt)
                afr[kt] = *(const s16x8*)&hA[w * 16 + m16][kt * 32 + q * 8];
            f32x4 acc[6];
            #pragma unroll
            for (int nt = 0; nt < 6; ++nt) acc[nt] = (f32x4){0.f, 0.f, 0.f, 0.f};
            #pragma unroll
            for (int nt = 0; nt < 6; ++nt)
                #pragma unroll
                for (int kt = 0; kt < 3; ++kt) {
                    s16x8 bf = *(const s16x8*)&sW2f[((nt * 3 + kt) * 64 + lane) * 8];
                    acc[nt] = __builtin_amdgcn_mfma_f32_16x16x32_bf16(
                        afr[kt], bf, acc[nt], 0, 0, 0);
                }
            #pragma unroll
            for (int nt = 0; nt < 6; ++nt) {
                int u = nt * 16 + m16;
                float bb = b2v[nt];
                #pragma unroll
                for (int r = 0; r < 4; ++r)
                    s_vf[w * 16 + q * 4 + r][u] = f2bf(acc[nt][r] + bb);
            }
        }
        __syncthreads();  // [B4] msg complete

        // 12. segment ballot (redundant per wave) + reduce, one atomic per
        //     (segment, unit)
        {
            int dl = s_dstM[cur][lane];
            int dp = (lane > 0) ? s_dstM[cur][lane - 1] : -1;
            bool bnd = (lane > 0) && (dl != dp);
            unsigned long long mask = __ballot(bnd);
            int nseg = (int)__popcll(mask) + 1;
            if (bnd) s_segstart[__popcll(mask & (~0ull >> (63 - lane)))] = lane;
            if (lane == 0) s_segstart[0] = 0;

            for (int idx = t; idx < nseg * HID; idx += 256) {
                int sg = idx / HID;
                int u = idx - sg * HID;
                int e0 = s_segstart[sg];
                int e1 = (sg + 1 < nseg) ? s_segstart[sg + 1] : 64;
                float sum = 0.f;
                for (int e = e0; e < e1; ++e) sum += bf2f(s_vf[e][u]);
                int dN = s_dstM[cur][e0];
                if (u < SDIM) atomicAdd(&out[dN * SDIM + u], sum);
                else atomicAdd(&out[N_NODESC * SDIM + dN * VDIM + (u - SDIM)], sum);
            }
        }

        // 13. rotate pipeline state
        edT1 = edT2; hvvT = hvvN; rcT = rcN; rsT = rsN; cur = nx;
        __syncthreads();  // loop-end: reduce done before next tile overwrites LDS
    }
}

// ---------------------------------------------------------------------------
// Mid-tier: f32 per-node precompute (4 tables) + unsorted atomic-scatter kernel.
__global__ __launch_bounds__(128) void node_precompute(
    const float* __restrict__ hs, const float* __restrict__ hv,
    const float* __restrict__ W1, const float* __restrict__ b1,
    __hip_bfloat16* __restrict__ Pp, __hip_bfloat16* __restrict__ Qt,
    __hip_bfloat16* __restrict__ Ut, __hip_bfloat16* __restrict__ Vt) {
    int n = blockIdx.x;
    __shared__ float s_hs[SDIM];
    __shared__ float s_hv[VDIM];
    int t = threadIdx.x;
    if (t < 64) s_hs[t] = hs[n * SDIM + t];
    else if (t < 96) s_hv[t - 64] = hv[n * VDIM + (t - 64)];
    __syncthreads();
    if (t < HID) {
        float p = b1[t], qq = 0.f, u = 0.f, v = 0.f;
        for (int k = 0; k < 64; ++k) {
            float x = s_hs[k];
            p += x * W1[k * HID + t];
            qq += x * W1[(64 + k) * HID + t];
        }
        for (int pr = 0; pr < 16; ++pr) {
            float x = s_hv[2 * pr], y = s_hv[2 * pr + 1];
            float wa = W1[(128 + 2 * pr) * HID + t];
            float wb = W1[(128 + 2 * pr + 1) * HID + t];
            u += x * wa + y * wb;
            v += x * wb - y * wa;
        }
        Pp[n * HID + t] = f2bf(p);
        Qt[n * HID + t] = f2bf(qq);
        Ut[n * HID + t] = f2bf(u);
        Vt[n * HID + t] = f2bf(v);
    }
}

__global__ void init_out(const float* __restrict__ hs, const float* __restrict__ hv,
                         float* __restrict__ out) {
    int i = blockIdx.x * blockDim.x + threadIdx.x;
    if (i >= N_NODESC * (SDIM + VDIM)) return;
    out[i] = (i < N_NODESC * SDIM) ? hs[i] : hv[i - N_NODESC * SDIM];
}

__global__ __launch_bounds__(256) void edge_kernel(
    const int* __restrict__ ei, const float* __restrict__ pos,
    const float* __restrict__ ori, const float* __restrict__ W1,
    const float* __restrict__ W2, const float* __restrict__ b2,
    const __hip_bfloat16* __restrict__ Pp, const __hip_bfloat16* __restrict__ Qt,
    const __hip_bfloat16* __restrict__ Ut, const __hip_bfloat16* __restrict__ Vt,
    const int* __restrict__ flag64, float* __restrict__ out) {
    __shared__ int s_src[64], s_dst[64];
    __shared__ float s_c[64], s_s[64], s_d[64], s_cg[64], s_sg[64];
    __shared__ float s_w1d[3][HID];
    __shared__ __hip_bfloat16 hA[64][104];
    __shared__ __hip_bfloat16 W2T[HID][104];

    const int t = threadIdx.x;
    const int lane = t & 63;
    const int w = t >> 6;
    const int m16 = lane & 15;
    const int q = lane >> 4;

    for (int idx = t; idx < HID * HID; idx += 256) {
        int k = idx / HID;
        int n = idx - k * HID;
        W2T[n][k] = f2bf(W2[idx]);
    }
    for (int idx = t; idx < 3 * HID; idx += 256) {
        int r = idx / HID, j = idx - r * HID;
        s_w1d[r][j] = W1[(160 + r) * HID + j];
    }
    __syncthreads();

    s16x8 bfr[6][3];
    for (int nt = 0; nt < 6; ++nt)
        for (int kt = 0; kt < 3; ++kt)
            bfr[nt][kt] = *(const s16x8*)&W2T[nt * 16 + m16][kt * 32 + q * 8];
    float b2v[6];
    for (int nt = 0; nt < 6; ++nt) b2v[nt] = b2[nt * 16 + m16];

    const bool i64 = (*flag64 != 0);
    const long long* ei64 = (const long long*)ei;

    for (int tile = blockIdx.x; tile < N_EDGESC / 64; tile += gridDim.x) {
        __syncthreads();

        if (t < 64) {
            int e = tile * 64 + t;
            int sN, dN;
            if (i64) { sN = (int)ei64[e]; dN = (int)ei64[N_EDGESC + e]; }
            else     { sN = ei[e];        dN = ei[N_EDGESC + e]; }
            s_src[t] = sN; s_dst[t] = dN;
            float ca, sa, cb, sb;
            __sincosf(2.0f * ori[dN], &sa, &ca);
            __sincosf(2.0f * ori[sN], &sb, &cb);
            s_c[t] = cb * ca + sb * sa;
            s_s[t] = sb * ca - cb * sa;
            float dx = pos[2 * sN] - pos[2 * dN];
            float dy = pos[2 * sN + 1] - pos[2 * dN + 1];
            float d2 = dx * dx + dy * dy;
            s_d[t] = sqrtf(d2) + 1e-6f;
            float c2f, s2f;
            if (d2 > 0.f) {
                float inv = 1.0f / d2;
                c2f = (dx * dx - dy * dy) * inv;
                s2f = 2.0f * dx * dy * inv;
            } else { c2f = 1.0f; s2f = 0.0f; }
            s_cg[t] = c2f * ca + s2f * sa;
            s_sg[t] = s2f * ca - c2f * sa;
        }
        __syncthreads();

        for (int p = 0; p < 24; ++p) {
            int idx = p * 256 + t;
            int e = idx / HID;
            int j = idx - e * HID;
            int sN = s_src[e], dN = s_dst[e];
            float pre = bf2f(Pp[sN * HID + j]) + bf2f(Qt[dN * HID + j])
                      + s_c[e] * bf2f(Ut[sN * HID + j])
                      + s_s[e] * bf2f(Vt[sN * HID + j])
                      + s_d[e] * s_w1d[0][j] + s_cg[e] * s_w1d[1][j]
                      + s_sg[e] * s_w1d[2][j];
            float h = pre / (1.0f + __expf(-pre));
            hA[e][j] = f2bf(h);
        }
        __syncthreads();

        f32x4 acc[6];
        for (int nt = 0; nt < 6; ++nt) acc[nt] = (f32x4){0.f, 0.f, 0.f, 0.f};
        s16x8 afr[3];
        for (int kt = 0; kt < 3; ++kt)
            afr[kt] = *(const s16x8*)&hA[w * 16 + m16][kt * 32 + q * 8];
        for (int nt = 0; nt < 6; ++nt)
            for (int kt = 0; kt < 3; ++kt)
                acc[nt] = __builtin_amdgcn_mfma_f32_16x16x32_bf16(
                    afr[kt], bfr[nt][kt], acc[nt], 0, 0, 0);

        for (int nt = 0; nt < 6; ++nt) {
            int u = nt * 16 + m16;
            for (int r = 0; r < 4; ++r) {
                int eloc = w * 16 + q * 4 + r;
                int dN = s_dst[eloc];
                float val = acc[nt][r] + b2v[nt];
                if (u < SDIM) atomicAdd(&out[dN * SDIM + u], val);
                else atomicAdd(&out[N_NODESC * SDIM + dN * VDIM + (u - SDIM)], val);
            }
        }
    }
}

// ---------------------------------------------------------------------------
// Fallback (ws too small for tables): fully per-edge, correct but slow.
__global__ __launch_bounds__(192) void edge_fallback(
    const int* __restrict__ ei, const float* __restrict__ hs,
    const float* __restrict__ hv, const float* __restrict__ pos,
    const float* __restrict__ ori, const float* __restrict__ W1,
    const float* __restrict__ b1, const float* __restrict__ W2,
    const float* __restrict__ b2, const int* __restrict__ flag64,
    float* __restrict__ out) {
    __shared__ float s_msg[IN_DIMC];
    __shared__ float s_h[HID];
    int e = blockIdx.x;
    int t = threadIdx.x;
    const bool i64 = (*flag64 != 0);
    int sN, dN;
    if (i64) {
        const long long* e64 = (const long long*)ei;
        sN = (int)e64[e]; dN = (int)e64[N_EDGESC + e];
    } else { sN = ei[e]; dN = ei[N_EDGESC + e]; }

    if (t < IN_DIMC) {
        if (t < 64) s_msg[t] = hs[sN * SDIM + t];
        else if (t < 128) s_msg[t] = hs[dN * SDIM + (t - 64)];
        else {
            float ca, sa, cb, sb;
            __sincosf(2.0f * ori[dN], &sa, &ca);
            __sincosf(2.0f * ori[sN], &sb, &cb);
            float c = cb * ca + sb * sa;
            float s = sb * ca - cb * sa;
            float dx = pos[2 * sN] - pos[2 * dN];
            float dy = pos[2 * sN + 1] - pos[2 * dN + 1];
            float d2 = dx * dx + dy * dy;
            if (t < 160) {
                int pr = (t - 128) >> 1;
                float x = hv[sN * VDIM + 2 * pr], y = hv[sN * VDIM + 2 * pr + 1];
                s_msg[t] = ((t & 1) == 0) ? (c * x - s * y) : (s * x + c * y);
            } else if (t == 160) s_msg[t] = sqrtf(d2) + 1e-6f;
            else {
                float c2f = 1.0f, s2f = 0.0f;
                if (d2 > 0.f) {
                    float inv = 1.0f / d2;
                    c2f = (dx * dx - dy * dy) * inv;
                    s2f = 2.0f * dx * dy * inv;
                }
                s_msg[t] = (t == 161) ? (c2f * ca + s2f * sa) : (s2f * ca - c2f * sa);
            }
        }
    }
    __syncthreads();
    if (t < HID) {
        float a = b1[t];
        for (int k = 0; k < IN_DIMC; ++k) a += s_msg[k] * W1[k * HID + t];
        s_h[t] = a / (1.0f + __expf(-a));
    }
    __syncthreads();
    if (t < HID) {
        float a = b2[t];
        for (int k = 0; k < HID; ++k) a += s_h[k] * W2[k * HID + t];
        if (t < SDIM) atomicAdd(&out[dN * SDIM + t], a);
        else atomicAdd(&out[N_NODESC * SDIM + dN * VDIM + (t - SDIM)], a);
    }
}

// ---------------------------------------------------------------------------
extern "C" void kernel_launch(void* const* d_in, const int* in_sizes, int n_in,
                              void* d_out, int out_size, void* d_ws, size_t ws_size,
                              hipStream_t stream) {
    const float* hs  = (const float*)d_in[0];
    const float* hv  = (const float*)d_in[1];
    const int*   ei  = (const int*)d_in[2];
    const float* pos = (const float*)d_in[3];
    const float* ori = (const float*)d_in[4];
    const float* W1  = (const float*)d_in[5];
    const float* b1  = (const float*)d_in[6];
    const float* W2  = (const float*)d_in[7];
    const float* b2  = (const float*)d_in[8];
    float* out = (float*)d_out;

    // sorted-tier workspace layout (256B-aligned chunks)
    const size_t SREC = (size_t)N_NODESC * 128 * sizeof(__hip_bfloat16);  // 12.8 MB
    const size_t QTB  = (size_t)N_NODESC * 96 * sizeof(__hip_bfloat16);   // 9.6 MB
    const size_t CNT  = ((size_t)N_NODESC * sizeof(int) + 255) & ~255ull; // 200 KB
    const size_t EDG  = (size_t)N_EDGESC * sizeof(int2);                  // 12.8 MB
    const size_t WBT2 = ((size_t)192 * 64 * 2 + 255) & ~255ull;
    const size_t W1CT = ((size_t)96 * 32 * 2 + 255) & ~255ull;
    const size_t W2TS = ((size_t)96 * 96 * 2 + 255) & ~255ull;
    const size_t SORT_WS = SREC + QTB + 2 * CNT + EDG + WBT2 + W1CT + W2TS + 256;

    const size_t TBL = (size_t)N_NODESC * HID * sizeof(__hip_bfloat16);   // 9.6 MB
    const bool big = ws_size >= 4 * TBL + 16;
    const bool srt = ws_size >= SORT_WS;

    if (srt) {
        char* ws = (char*)d_ws;
        __hip_bfloat16* SrcRec = (__hip_bfloat16*)(ws);
        __hip_bfloat16* Qt     = (__hip_bfloat16*)(ws + SREC);
        int* counts            = (int*)(ws + SREC + QTB);
        int* cur               = (int*)(ws + SREC + QTB + CNT);
        int2* edges            = (int2*)(ws + SREC + QTB + 2 * CNT);
        __hip_bfloat16* WbT2   = (__hip_bfloat16*)(ws + SREC + QTB + 2 * CNT + EDG);
        __hip_bfloat16* W1cT   = (__hip_bfloat16*)(ws + SREC + QTB + 2 * CNT + EDG + WBT2);
        __hip_bfloat16* W2Tb   = (__hip_bfloat16*)(ws + SREC + QTB + 2 * CNT + EDG + WBT2 + W1CT);
        int* flag              = (int*)(ws + SREC + QTB + 2 * CNT + EDG + WBT2 + W1CT + W2TS);

        detect_kernel<<<1, 64, 0, stream>>>(ei, flag);
        zero_counts<<<(N_NODESC + 255) / 256, 256, 0, stream>>>(counts);
        fused_init<<<(N_NODESC * (SDIM + VDIM) + 255) / 256, 256, 0, stream>>>(
            hs, hv, out, counts, W1, W2, SrcRec, WbT2, W1cT, W2Tb, ei, flag);
        scan_kernel<<<1, 1024, 0, stream>>>(counts, cur);
        scatter_kernel<<<N_EDGESC / 256, 256, 0, stream>>>(ei, flag, cur, edges);
        node_precompute_mfma<<<(N_NODESC + 63) / 64, 256, 0, stream>>>(
            hs, WbT2, b1, SrcRec, Qt);
        edge_kernel_sorted<<<GRID_E, 256, 0, stream>>>(edges, pos, ori, W1, W2Tb, b2,
                                                       SrcRec, Qt, W1cT, out);
    } else if (big) {
        char* ws = (char*)d_ws;
        __hip_bfloat16* Pp = (__hip_bfloat16*)(ws);
        __hip_bfloat16* Qt = (__hip_bfloat16*)(ws + TBL);
        __hip_bfloat16* Ut = (__hip_bfloat16*)(ws + 2 * TBL);
        __hip_bfloat16* Vt = (__hip_bfloat16*)(ws + 3 * TBL);
        int* flag = (int*)(ws + 4 * TBL);
        init_out<<<(N_NODESC * (SDIM + VDIM) + 255) / 256, 256, 0, stream>>>(hs, hv, out);
        detect_kernel<<<1, 64, 0, stream>>>(ei, flag);
        node_precompute<<<N_NODESC, 128, 0, stream>>>(hs, hv, W1, b1, Pp, Qt, Ut, Vt);
        edge_kernel<<<2500, 256, 0, stream>>>(ei, pos, ori, W1, W2, b2,
                                              Pp, Qt, Ut, Vt, flag, out);
    } else {
        int* flag = (int*)d_ws;
        init_out<<<(N_NODESC * (SDIM + VDIM) + 255) / 256, 256, 0, stream>>>(hs, hv, out);
        detect_kernel<<<1, 64, 0, stream>>>(ei, flag);
        edge_fallback<<<N_EDGESC, 192, 0, stream>>>(ei, hs, hv, pos, ori, W1, b1,
                                                    W2, b2, flag, out);
    }
}

// Round 7
// 607.083 us; speedup vs baseline: 1.2943x; 1.0977x over previous
//
#include <hip/hip_runtime.h>
#include <hip/hip_bf16.h>

#define N_NODESC 50000
#define N_EDGESC 1600000
#define SDIM 64
#define VDIM 32
#define HID 96
#define IN_DIMC 163

#define GRID_E 6250
#define TPB_E 4            // tiles per block (25000 tiles / 6250 blocks)
#define NXCD 8
#define XQ (GRID_E / NXCD) // 781
#define XR (GRID_E % NXCD) // 2

typedef float f32x4 __attribute__((ext_vector_type(4)));
typedef short s16x8 __attribute__((ext_vector_type(8)));

__device__ __forceinline__ float bf2f(__hip_bfloat16 x) { return __bfloat162float(x); }
__device__ __forceinline__ __hip_bfloat16 f2bf(float x) { return __float2bfloat16(x); }
__device__ __forceinline__ float bfbits2f(short b) {
    unsigned u = ((unsigned)(unsigned short)b) << 16;
    return __builtin_bit_cast(float, u);
}
__device__ __forceinline__ short f2bfbits(float x) {
    __hip_bfloat16 h = __float2bfloat16(x);
    return *(const short*)&h;
}

// ---------------------------------------------------------------------------
// Detect int64 layout + zero the histogram counters (merged; one launch).
__global__ void detect_zero(const int* ei, int* flag, int* __restrict__ counts) {
    int i = blockIdx.x * blockDim.x + threadIdx.x;
    if (i < N_NODESC) counts[i] = 0;
    if (i == 0) {
        int z = 1;
        for (int k = 0; k < 64; ++k) {
            if (ei[2 * k + 1] != 0) { z = 0; break; }
        }
        *flag = z;  // 1 -> int64 layout
    }
}

// ---------------------------------------------------------------------------
// Fused one-shot prep for the sorted tier (also does the dst histogram).
//  W1cgT [96][64] bf16: cols 0-31 = W1c^T (vector block), 32-34 = geo rows
//  (dist, cos, sin weight rows), 35-63 = 0. Feeds the K=64 vec+geo MFMA.
__global__ void fused_init(const float* __restrict__ hs, const float* __restrict__ hv,
                           float* __restrict__ out, int* __restrict__ counts,
                           const float* __restrict__ W1, const float* __restrict__ W2,
                           __hip_bfloat16* __restrict__ SrcRec,
                           __hip_bfloat16* __restrict__ WbT2,
                           __hip_bfloat16* __restrict__ W1cgT,
                           __hip_bfloat16* __restrict__ W2Tb,
                           const int* __restrict__ ei, const int* __restrict__ flag64) {
    int i = blockIdx.x * blockDim.x + threadIdx.x;
    if (i < N_NODESC * (SDIM + VDIM))
        out[i] = (i < N_NODESC * SDIM) ? hs[i] : hv[i - N_NODESC * SDIM];
    if (i < N_NODESC * VDIM) {
        int n = i >> 5, f = i & 31;
        SrcRec[n * 128 + 96 + f] = f2bf(hv[i]);
    }
    if (i < 192 * 64) {
        int n = i >> 6, k = i & 63;
        float val = (n < 96) ? W1[k * HID + n] : W1[(64 + k) * HID + (n - 96)];
        WbT2[i] = f2bf(val);
    }
    if (i < 96 * 64) {
        int n = i >> 6, k = i & 63;
        float val = 0.f;
        if (k < 32) val = W1[(128 + k) * HID + n];
        else if (k < 35) val = W1[(160 + (k - 32)) * HID + n];
        W1cgT[i] = f2bf(val);
    }
    if (i < 96 * 96) {
        int n = i / 96, k = i - (i / 96) * 96;
        W2Tb[i] = f2bf(W2[k * HID + n]);
    }
    if (i < N_EDGESC) {
        int dN;
        if (*flag64) dN = (int)((const long long*)ei)[N_EDGESC + i];
        else dN = ei[N_EDGESC + i];
        atomicAdd(&counts[dN], 1);
    }
}

// ---------------------------------------------------------------------------
// MFMA node precompute (K=64): [P|Q] = hs_bf16 @ [W1a|W1b]; P (+b1) ->
// SrcRec[n][0:96), Q -> Qt[n][:]. Output staged in LDS, stored coalesced.
__global__ __launch_bounds__(256, 2) void node_precompute_mfma(
    const float* __restrict__ hs, const __hip_bfloat16* __restrict__ WbT2,
    const float* __restrict__ b1,
    __hip_bfloat16* __restrict__ SrcRec, __hip_bfloat16* __restrict__ Qt) {
    __shared__ __hip_bfloat16 sA[64][72];
    __shared__ __hip_bfloat16 sOut[64][200];  // 192 used
    const int t = threadIdx.x;
    const int lane = t & 63;
    const int w = t >> 6;
    const int m16 = lane & 15;
    const int q = lane >> 4;
    const int nb = blockIdx.x * 64;

    for (int idx = t; idx < 64 * 64; idx += 256) {
        int node = idx >> 6, f = idx & 63;
        int g = nb + node;
        sA[node][f] = f2bf(g < N_NODESC ? hs[g * SDIM + f] : 0.f);
    }
    __syncthreads();

    s16x8 bfr[3][2];
    float b1v[3];
    for (int nt = 0; nt < 3; ++nt) {
        int n_out = w * 48 + nt * 16 + m16;
        for (int kt = 0; kt < 2; ++kt)
            bfr[nt][kt] = *(const s16x8*)&WbT2[n_out * 64 + kt * 32 + q * 8];
        b1v[nt] = (n_out < 96) ? b1[n_out] : 0.f;
    }

    for (int ms = 0; ms < 4; ++ms) {
        s16x8 afr[2];
        for (int kt = 0; kt < 2; ++kt)
            afr[kt] = *(const s16x8*)&sA[ms * 16 + m16][kt * 32 + q * 8];
        f32x4 acc[3];
        for (int nt = 0; nt < 3; ++nt) acc[nt] = (f32x4){0.f, 0.f, 0.f, 0.f};
        for (int nt = 0; nt < 3; ++nt)
            for (int kt = 0; kt < 2; ++kt)
                acc[nt] = __builtin_amdgcn_mfma_f32_16x16x32_bf16(
                    afr[kt], bfr[nt][kt], acc[nt], 0, 0, 0);
        for (int nt = 0; nt < 3; ++nt) {
            int n_out = w * 48 + nt * 16 + m16;
            for (int r = 0; r < 4; ++r)
                sOut[ms * 16 + q * 4 + r][n_out] = f2bf(acc[nt][r] + b1v[nt]);
        }
    }
    __syncthreads();

    for (int idx = t; idx < 64 * 12; idx += 256) {
        int node = idx / 12, ch = idx - (idx / 12) * 12;
        int g = nb + node;
        if (g < N_NODESC)
            *(s16x8*)&SrcRec[g * 128 + ch * 8] = *(const s16x8*)&sOut[node][ch * 8];
    }
    for (int idx = t; idx < 64 * 12; idx += 256) {
        int node = idx / 12, ch = idx - (idx / 12) * 12;
        int g = nb + node;
        if (g < N_NODESC)
            *(s16x8*)&Qt[g * 96 + ch * 8] = *(const s16x8*)&sOut[node][96 + ch * 8];
    }
}

// ---------------------------------------------------------------------------
__global__ __launch_bounds__(1024) void scan_kernel(
    const int* __restrict__ counts, int* __restrict__ cur) {
    __shared__ int part[1024];
    const int t = threadIdx.x;
    const int CH = (N_NODESC + 1023) / 1024;  // 49
    int lo = t * CH;
    int hi = lo + CH; if (hi > N_NODESC) hi = N_NODESC;
    int s = 0;
    for (int i = lo; i < hi; ++i) s += counts[i];
    part[t] = s;
    __syncthreads();
    for (int d = 1; d < 1024; d <<= 1) {
        int v = (t >= d) ? part[t - d] : 0;
        __syncthreads();
        part[t] += v;
        __syncthreads();
    }
    int run = (t == 0) ? 0 : part[t - 1];
    for (int i = lo; i < hi; ++i) {
        int c = counts[i];
        cur[i] = run;
        run += c;
    }
}

__global__ __launch_bounds__(256) void scatter_kernel(
    const int* __restrict__ ei, const int* __restrict__ flag64,
    int* __restrict__ cur, int2* __restrict__ edges) {
    int e = blockIdx.x * blockDim.x + threadIdx.x;
    if (e >= N_EDGESC) return;
    int sN, dN;
    if (*flag64) {
        const long long* e64 = (const long long*)ei;
        sN = (int)e64[e]; dN = (int)e64[N_EDGESC + e];
    } else { sN = ei[e]; dN = ei[N_EDGESC + e]; }
    int p = atomicAdd(&cur[dN], 1);
    edges[p] = make_int2(sN, dN);
}

// ---------------------------------------------------------------------------
// Main edge kernel (dst-sorted, chunked+XCD-swizzled, cross-tile prefetch).
// Layer-1 is now fully MFMA-shaped: a K=64 MFMA computes the vec+geo
// contribution (A = [rot-hv | d,cg,sg | 0...]), so phase-1b is only
// silu(P + Q + V) — no per-unit geo FMAs or weight LDS reads.
// hVG shares LDS storage with hA (hVG consumed before hA is written).
__global__ __launch_bounds__(256, 3) void edge_kernel_sorted(
    const int2* __restrict__ edges,
    const float* __restrict__ pos, const float* __restrict__ ori,
    const __hip_bfloat16* __restrict__ W2Tb, const float* __restrict__ b2,
    const __hip_bfloat16* __restrict__ SrcRec, const __hip_bfloat16* __restrict__ Qt,
    const __hip_bfloat16* __restrict__ W1cgT,
    float* __restrict__ out) {
    __shared__ int s_srcM[2][64], s_dstM[2][64];
    __shared__ alignas(16) __hip_bfloat16 hA[64][104];    // hVG (staging) then silu(layer1)
    __shared__ alignas(16) __hip_bfloat16 s_vf[64][104];  // vec+geo contrib / msg
    __shared__ alignas(16) short sW2f[18 * 64 * 8];       // W2 frags, lane-packed
    __shared__ int s_segstart[66];

    const int t = threadIdx.x;
    const int lane = t & 63;
    const int w = t >> 6;        // wave id 0..3
    const int m16 = lane & 15;
    const int q = lane >> 4;
    const int el = t >> 2;       // edge-role: edge index 0..63
    const int quad = t & 3;      // edge-role: quad 0..3

    // W2 fragments -> LDS, packed by (frag, lane): ds_read_b128 at lane*16B.
    if (w == 0) {
        for (int f = 0; f < 18; ++f) {
            int nt = f / 3, kt = f - (f / 3) * 3;
            *(s16x8*)&sW2f[(f * 64 + lane) * 8] =
                *(const s16x8*)&W2Tb[(nt * 16 + m16) * 96 + kt * 32 + q * 8];
        }
    }
    // W1cg fragments (K=64 -> 2 per nt) in registers (48 VGPR).
    s16x8 bfrC[6][2];
    #pragma unroll
    for (int nt = 0; nt < 6; ++nt)
        #pragma unroll
        for (int kt = 0; kt < 2; ++kt)
            bfrC[nt][kt] = *(const s16x8*)&W1cgT[(nt * 16 + m16) * 64 + kt * 32 + q * 8];
    float b2v[6];
    #pragma unroll
    for (int nt = 0; nt < 6; ++nt) b2v[nt] = b2[nt * 16 + m16];

    // Chunked, XCD-swizzled tile range.
    int b = blockIdx.x;
    int xcd = b & 7, bi = b >> 3;
    int c = (xcd < XR) ? (xcd * (XQ + 1) + bi)
                       : (XR * (XQ + 1) + (xcd - XR) * XQ + bi);
    const int tile0 = c * TPB_E;

    // ---- prologue: stage tile 0 meta, prefetch tile 1's edge ids ----
    int2 edT1;            // edges for tile tl+1 (edge-role)
    s16x8 hvvT;           // raw hv gather for current tile
    float rcT, rsT;       // rotation coeffs (current tile)
    float gdT, gcgT, gsgT;// geo features (current tile)
    {
        int2 edT = edges[tile0 * 64 + el];
        edT1 = edges[(tile0 + 1) * 64 + el];
        hvvT = *(const s16x8*)&SrcRec[edT.x * 128 + 96 + quad * 8];
        int sN = edT.x, dN = edT.y;
        float ca, sa, cb, sb;
        __sincosf(2.0f * ori[dN], &sa, &ca);
        __sincosf(2.0f * ori[sN], &sb, &cb);
        rcT = cb * ca + sb * sa;
        rsT = sb * ca - cb * sa;
        float dx = pos[2 * sN] - pos[2 * dN];
        float dy = pos[2 * sN + 1] - pos[2 * dN + 1];
        float d2 = dx * dx + dy * dy;
        gdT = sqrtf(d2) + 1e-6f;
        float c2f, s2f;
        if (d2 > 0.f) {
            float inv = 1.0f / d2;
            c2f = (dx * dx - dy * dy) * inv;
            s2f = 2.0f * dx * dy * inv;
        } else { c2f = 1.0f; s2f = 0.0f; }
        gcgT = c2f * ca + s2f * sa;
        gsgT = s2f * ca - c2f * sa;
        if (quad == 0) { s_srcM[0][el] = sN; s_dstM[0][el] = dN; }
    }
    __syncthreads();
    // Issue P/Q gathers for tile 0.
    s16x8 pqP[3], pqQ[3];
    #pragma unroll
    for (int i2 = 0; i2 < 3; ++i2) {
        int item = i2 * 256 + t;
        int e = item / 12;
        int j = (item - e * 12) * 8;
        pqP[i2] = *(const s16x8*)&SrcRec[s_srcM[0][e] * 128 + j];
        pqQ[i2] = *(const s16x8*)&Qt[s_dstM[0][e] * 96 + j];
    }

    int cur = 0;
    for (int tl = 0; tl < TPB_E; ++tl) {
        const int nx = cur ^ 1;
        const int tlN2 = (tl + 2 < TPB_E) ? tl + 2 : TPB_E - 1;

        // 1. rotate hv(T) + geo -> hVG rows (stored in hA's LDS; own-wave rows)
        {
            s16x8 rv;
            #pragma unroll
            for (int p2 = 0; p2 < 4; ++p2) {
                float x = bfbits2f(hvvT[2 * p2]), y = bfbits2f(hvvT[2 * p2 + 1]);
                rv[2 * p2]     = f2bfbits(rcT * x - rsT * y);
                rv[2 * p2 + 1] = f2bfbits(rsT * x + rcT * y);
            }
            *(s16x8*)&hA[el][quad * 8] = rv;
            s16x8 up = (s16x8){0, 0, 0, 0, 0, 0, 0, 0};
            if (quad == 0) {
                up[0] = f2bfbits(gdT); up[1] = f2bfbits(gcgT); up[2] = f2bfbits(gsgT);
            }
            *(s16x8*)&hA[el][32 + quad * 8] = up;
        }
        // 2/3. prefetch edges(T+2) and hv(T+1) — long-latency, used next iter
        int2 edT2 = edges[(tile0 + tlN2) * 64 + el];
        s16x8 hvvN = *(const s16x8*)&SrcRec[edT1.x * 128 + 96 + quad * 8];
        // 4. vec+geo via K=64 MFMA (2 chained K=32) -> s_vf (own-wave rows)
        {
            s16x8 afr0 = *(const s16x8*)&hA[w * 16 + m16][q * 8];
            s16x8 afr1 = *(const s16x8*)&hA[w * 16 + m16][32 + q * 8];
            #pragma unroll
            for (int nt = 0; nt < 6; ++nt) {
                f32x4 a1 = __builtin_amdgcn_mfma_f32_16x16x32_bf16(
                    afr0, bfrC[nt][0], (f32x4){0.f, 0.f, 0.f, 0.f}, 0, 0, 0);
                a1 = __builtin_amdgcn_mfma_f32_16x16x32_bf16(
                    afr1, bfrC[nt][1], a1, 0, 0, 0);
                int u = nt * 16 + m16;
                #pragma unroll
                for (int r = 0; r < 4; ++r)
                    s_vf[w * 16 + q * 4 + r][u] = f2bf(a1[r]);
            }
        }
        // 5. meta + rotation + geo for T+1 -> regs + index LDS
        float rcN, rsN, gdN, gcgN, gsgN;
        {
            int sN = edT1.x, dN = edT1.y;
            float ca, sa, cb, sb;
            __sincosf(2.0f * ori[dN], &sa, &ca);
            __sincosf(2.0f * ori[sN], &sb, &cb);
            rcN = cb * ca + sb * sa;
            rsN = sb * ca - cb * sa;
            float dx = pos[2 * sN] - pos[2 * dN];
            float dy = pos[2 * sN + 1] - pos[2 * dN + 1];
            float d2 = dx * dx + dy * dy;
            gdN = sqrtf(d2) + 1e-6f;
            float c2f, s2f;
            if (d2 > 0.f) {
                float inv = 1.0f / d2;
                c2f = (dx * dx - dy * dy) * inv;
                s2f = 2.0f * dx * dy * inv;
            } else { c2f = 1.0f; s2f = 0.0f; }
            gcgN = c2f * ca + s2f * sa;
            gsgN = s2f * ca - c2f * sa;
            if (quad == 0) { s_srcM[nx][el] = sN; s_dstM[nx][el] = dN; }
        }
        __syncthreads();  // [B2] s_vf + meta[nx] visible

        // 7. phase-1b: silu(P + Q + V) -> hA (overwrites hVG; safe post-B2)
        #pragma unroll
        for (int i2 = 0; i2 < 3; ++i2) {
            int item = i2 * 256 + t;
            int e = item / 12;
            int j = (item - e * 12) * 8;
            s16x8 Vv = *(const s16x8*)&s_vf[e][j];
            s16x8 hb;
            #pragma unroll
            for (int k2 = 0; k2 < 8; ++k2) {
                float pre = bfbits2f(pqP[i2][k2]) + bfbits2f(pqQ[i2][k2])
                          + bfbits2f(Vv[k2]);
                float h = pre / (1.0f + __expf(-pre));  // silu
                hb[k2] = f2bfbits(h);
            }
            *(s16x8*)&hA[e][j] = hb;
        }
        __syncthreads();  // [B3] hA visible

        // 9. prefetch P/Q for T+1 (indices from meta[nx]); overlaps the MFMA.
        #pragma unroll
        for (int i2 = 0; i2 < 3; ++i2) {
            int item = i2 * 256 + t;
            int e = item / 12;
            int j = (item - e * 12) * 8;
            pqP[i2] = *(const s16x8*)&SrcRec[s_srcM[nx][e] * 128 + j];
            pqQ[i2] = *(const s16x8*)&Qt[s_dstM[nx][e] * 96 + j];
        }
        // 10. layer-2 MFMA (B frags from LDS) -> msg overwrites s_vf
        {
            s16x8 afr[3];
            #pragma unroll
            for (int kt = 0; kt < 3; ++kt)
                afr[kt] = *(const s16x8*)&hA[w * 16 + m16][kt * 32 + q * 8];
            f32x4 acc[6];
            #pragma unroll
            for (int nt = 0; nt < 6; ++nt) acc[nt] = (f32x4){0.f, 0.f, 0.f, 0.f};
            #pragma unroll
            for (int nt = 0; nt < 6; ++nt)
                #pragma unroll
                for (int kt = 0; kt < 3; ++kt) {
                    s16x8 bf = *(const s16x8*)&sW2f[((nt * 3 + kt) * 64 + lane) * 8];
                    acc[nt] = __builtin_amdgcn_mfma_f32_16x16x32_bf16(
                        afr[kt], bf, acc[nt], 0, 0, 0);
                }
            #pragma unroll
            for (int nt = 0; nt < 6; ++nt) {
                int u = nt * 16 + m16;
                float bb = b2v[nt];
                #pragma unroll
                for (int r = 0; r < 4; ++r)
                    s_vf[w * 16 + q * 4 + r][u] = f2bf(acc[nt][r] + bb);
            }
        }
        __syncthreads();  // [B4] msg complete

        // 12. segment ballot (redundant per wave) + reduce, one atomic per
        //     (segment, unit)
        {
            int dl = s_dstM[cur][lane];
            int dp = (lane > 0) ? s_dstM[cur][lane - 1] : -1;
            bool bnd = (lane > 0) && (dl != dp);
            unsigned long long mask = __ballot(bnd);
            int nseg = (int)__popcll(mask) + 1;
            if (bnd) s_segstart[__popcll(mask & (~0ull >> (63 - lane)))] = lane;
            if (lane == 0) s_segstart[0] = 0;

            for (int idx = t; idx < nseg * HID; idx += 256) {
                int sg = idx / HID;
                int u = idx - sg * HID;
                int e0 = s_segstart[sg];
                int e1 = (sg + 1 < nseg) ? s_segstart[sg + 1] : 64;
                float sum = 0.f;
                for (int e = e0; e < e1; ++e) sum += bf2f(s_vf[e][u]);
                int dN = s_dstM[cur][e0];
                if (u < SDIM) atomicAdd(&out[dN * SDIM + u], sum);
                else atomicAdd(&out[N_NODESC * SDIM + dN * VDIM + (u - SDIM)], sum);
            }
        }

        // 13. rotate pipeline state
        edT1 = edT2; hvvT = hvvN;
        rcT = rcN; rsT = rsN; gdT = gdN; gcgT = gcgN; gsgT = gsgN;
        cur = nx;
        __syncthreads();  // loop-end: reduce done before next tile overwrites LDS
    }
}

// ---------------------------------------------------------------------------
// Mid-tier: f32 per-node precompute (4 tables) + unsorted atomic-scatter kernel.
__global__ __launch_bounds__(128) void node_precompute(
    const float* __restrict__ hs, const float* __restrict__ hv,
    const float* __restrict__ W1, const float* __restrict__ b1,
    __hip_bfloat16* __restrict__ Pp, __hip_bfloat16* __restrict__ Qt,
    __hip_bfloat16* __restrict__ Ut, __hip_bfloat16* __restrict__ Vt) {
    int n = blockIdx.x;
    __shared__ float s_hs[SDIM];
    __shared__ float s_hv[VDIM];
    int t = threadIdx.x;
    if (t < 64) s_hs[t] = hs[n * SDIM + t];
    else if (t < 96) s_hv[t - 64] = hv[n * VDIM + (t - 64)];
    __syncthreads();
    if (t < HID) {
        float p = b1[t], qq = 0.f, u = 0.f, v = 0.f;
        for (int k = 0; k < 64; ++k) {
            float x = s_hs[k];
            p += x * W1[k * HID + t];
            qq += x * W1[(64 + k) * HID + t];
        }
        for (int pr = 0; pr < 16; ++pr) {
            float x = s_hv[2 * pr], y = s_hv[2 * pr + 1];
            float wa = W1[(128 + 2 * pr) * HID + t];
            float wb = W1[(128 + 2 * pr + 1) * HID + t];
            u += x * wa + y * wb;
            v += x * wb - y * wa;
        }
        Pp[n * HID + t] = f2bf(p);
        Qt[n * HID + t] = f2bf(qq);
        Ut[n * HID + t] = f2bf(u);
        Vt[n * HID + t] = f2bf(v);
    }
}

__global__ void init_out(const float* __restrict__ hs, const float* __restrict__ hv,
                         float* __restrict__ out) {
    int i = blockIdx.x * blockDim.x + threadIdx.x;
    if (i >= N_NODESC * (SDIM + VDIM)) return;
    out[i] = (i < N_NODESC * SDIM) ? hs[i] : hv[i - N_NODESC * SDIM];
}

__global__ void detect_kernel(const int* ei, int* flag) {
    if (blockIdx.x == 0 && threadIdx.x == 0) {
        int z = 1;
        for (int k = 0; k < 64; ++k) {
            if (ei[2 * k + 1] != 0) { z = 0; break; }
        }
        *flag = z;
    }
}

__global__ __launch_bounds__(256) void edge_kernel(
    const int* __restrict__ ei, const float* __restrict__ pos,
    const float* __restrict__ ori, const float* __restrict__ W1,
    const float* __restrict__ W2, const float* __restrict__ b2,
    const __hip_bfloat16* __restrict__ Pp, const __hip_bfloat16* __restrict__ Qt,
    const __hip_bfloat16* __restrict__ Ut, const __hip_bfloat16* __restrict__ Vt,
    const int* __restrict__ flag64, float* __restrict__ out) {
    __shared__ int s_src[64], s_dst[64];
    __shared__ float s_c[64], s_s[64], s_d[64], s_cg[64], s_sg[64];
    __shared__ float s_w1d[3][HID];
    __shared__ __hip_bfloat16 hA[64][104];
    __shared__ __hip_bfloat16 W2T[HID][104];

    const int t = threadIdx.x;
    const int lane = t & 63;
    const int w = t >> 6;
    const int m16 = lane & 15;
    const int q = lane >> 4;

    for (int idx = t; idx < HID * HID; idx += 256) {
        int k = idx / HID;
        int n = idx - k * HID;
        W2T[n][k] = f2bf(W2[idx]);
    }
    for (int idx = t; idx < 3 * HID; idx += 256) {
        int r = idx / HID, j = idx - r * HID;
        s_w1d[r][j] = W1[(160 + r) * HID + j];
    }
    __syncthreads();

    s16x8 bfr[6][3];
    for (int nt = 0; nt < 6; ++nt)
        for (int kt = 0; kt < 3; ++kt)
            bfr[nt][kt] = *(const s16x8*)&W2T[nt * 16 + m16][kt * 32 + q * 8];
    float b2v[6];
    for (int nt = 0; nt < 6; ++nt) b2v[nt] = b2[nt * 16 + m16];

    const bool i64 = (*flag64 != 0);
    const long long* ei64 = (const long long*)ei;

    for (int tile = blockIdx.x; tile < N_EDGESC / 64; tile += gridDim.x) {
        __syncthreads();

        if (t < 64) {
            int e = tile * 64 + t;
            int sN, dN;
            if (i64) { sN = (int)ei64[e]; dN = (int)ei64[N_EDGESC + e]; }
            else     { sN = ei[e];        dN = ei[N_EDGESC + e]; }
            s_src[t] = sN; s_dst[t] = dN;
            float ca, sa, cb, sb;
            __sincosf(2.0f * ori[dN], &sa, &ca);
            __sincosf(2.0f * ori[sN], &sb, &cb);
            s_c[t] = cb * ca + sb * sa;
            s_s[t] = sb * ca - cb * sa;
            float dx = pos[2 * sN] - pos[2 * dN];
            float dy = pos[2 * sN + 1] - pos[2 * dN + 1];
            float d2 = dx * dx + dy * dy;
            s_d[t] = sqrtf(d2) + 1e-6f;
            float c2f, s2f;
            if (d2 > 0.f) {
                float inv = 1.0f / d2;
                c2f = (dx * dx - dy * dy) * inv;
                s2f = 2.0f * dx * dy * inv;
            } else { c2f = 1.0f; s2f = 0.0f; }
            s_cg[t] = c2f * ca + s2f * sa;
            s_sg[t] = s2f * ca - c2f * sa;
        }
        __syncthreads();

        for (int p = 0; p < 24; ++p) {
            int idx = p * 256 + t;
            int e = idx / HID;
            int j = idx - e * HID;
            int sN = s_src[e], dN = s_dst[e];
            float pre = bf2f(Pp[sN * HID + j]) + bf2f(Qt[dN * HID + j])
                      + s_c[e] * bf2f(Ut[sN * HID + j])
                      + s_s[e] * bf2f(Vt[sN * HID + j])
                      + s_d[e] * s_w1d[0][j] + s_cg[e] * s_w1d[1][j]
                      + s_sg[e] * s_w1d[2][j];
            float h = pre / (1.0f + __expf(-pre));
            hA[e][j] = f2bf(h);
        }
        __syncthreads();

        f32x4 acc[6];
        for (int nt = 0; nt < 6; ++nt) acc[nt] = (f32x4){0.f, 0.f, 0.f, 0.f};
        s16x8 afr[3];
        for (int kt = 0; kt < 3; ++kt)
            afr[kt] = *(const s16x8*)&hA[w * 16 + m16][kt * 32 + q * 8];
        for (int nt = 0; nt < 6; ++nt)
            for (int kt = 0; kt < 3; ++kt)
                acc[nt] = __builtin_amdgcn_mfma_f32_16x16x32_bf16(
                    afr[kt], bfr[nt][kt], acc[nt], 0, 0, 0);

        for (int nt = 0; nt < 6; ++nt) {
            int u = nt * 16 + m16;
            for (int r = 0; r < 4; ++r) {
                int eloc = w * 16 + q * 4 + r;
                int dN = s_dst[eloc];
                float val = acc[nt][r] + b2v[nt];
                if (u < SDIM) atomicAdd(&out[dN * SDIM + u], val);
                else atomicAdd(&out[N_NODESC * SDIM + dN * VDIM + (u - SDIM)], val);
            }
        }
    }
}

// ---------------------------------------------------------------------------
// Fallback (ws too small for tables): fully per-edge, correct but slow.
__global__ __launch_bounds__(192) void edge_fallback(
    const int* __restrict__ ei, const float* __restrict__ hs,
    const float* __restrict__ hv, const float* __restrict__ pos,
    const float* __restrict__ ori, const float* __restrict__ W1,
    const float* __restrict__ b1, const float* __restrict__ W2,
    const float* __restrict__ b2, const int* __restrict__ flag64,
    float* __restrict__ out) {
    __shared__ float s_msg[IN_DIMC];
    __shared__ float s_h[HID];
    int e = blockIdx.x;
    int t = threadIdx.x;
    const bool i64 = (*flag64 != 0);
    int sN, dN;
    if (i64) {
        const long long* e64 = (const long long*)ei;
        sN = (int)e64[e]; dN = (int)e64[N_EDGESC + e];
    } else { sN = ei[e]; dN = ei[N_EDGESC + e]; }

    if (t < IN_DIMC) {
        if (t < 64) s_msg[t] = hs[sN * SDIM + t];
        else if (t < 128) s_msg[t] = hs[dN * SDIM + (t - 64)];
        else {
            float ca, sa, cb, sb;
            __sincosf(2.0f * ori[dN], &sa, &ca);
            __sincosf(2.0f * ori[sN], &sb, &cb);
            float c = cb * ca + sb * sa;
            float s = sb * ca - cb * sa;
            float dx = pos[2 * sN] - pos[2 * dN];
            float dy = pos[2 * sN + 1] - pos[2 * dN + 1];
            float d2 = dx * dx + dy * dy;
            if (t < 160) {
                int pr = (t - 128) >> 1;
                float x = hv[sN * VDIM + 2 * pr], y = hv[sN * VDIM + 2 * pr + 1];
                s_msg[t] = ((t & 1) == 0) ? (c * x - s * y) : (s * x + c * y);
            } else if (t == 160) s_msg[t] = sqrtf(d2) + 1e-6f;
            else {
                float c2f = 1.0f, s2f = 0.0f;
                if (d2 > 0.f) {
                    float inv = 1.0f / d2;
                    c2f = (dx * dx - dy * dy) * inv;
                    s2f = 2.0f * dx * dy * inv;
                }
                s_msg[t] = (t == 161) ? (c2f * ca + s2f * sa) : (s2f * ca - c2f * sa);
            }
        }
    }
    __syncthreads();
    if (t < HID) {
        float a = b1[t];
        for (int k = 0; k < IN_DIMC; ++k) a += s_msg[k] * W1[k * HID + t];
        s_h[t] = a / (1.0f + __expf(-a));
    }
    __syncthreads();
    if (t < HID) {
        float a = b2[t];
        for (int k = 0; k < HID; ++k) a += s_h[k] * W2[k * HID + t];
        if (t < SDIM) atomicAdd(&out[dN * SDIM + t], a);
        else atomicAdd(&out[N_NODESC * SDIM + dN * VDIM + (t - SDIM)], a);
    }
}

// ---------------------------------------------------------------------------
extern "C" void kernel_launch(void* const* d_in, const int* in_sizes, int n_in,
                              void* d_out, int out_size, void* d_ws, size_t ws_size,
                              hipStream_t stream) {
    const float* hs  = (const float*)d_in[0];
    const float* hv  = (const float*)d_in[1];
    const int*   ei  = (const int*)d_in[2];
    const float* pos = (const float*)d_in[3];
    const float* ori = (const float*)d_in[4];
    const float* W1  = (const float*)d_in[5];
    const float* b1  = (const float*)d_in[6];
    const float* W2  = (const float*)d_in[7];
    const float* b2  = (const float*)d_in[8];
    float* out = (float*)d_out;

    // sorted-tier workspace layout (256B-aligned chunks)
    const size_t SREC = (size_t)N_NODESC * 128 * sizeof(__hip_bfloat16);  // 12.8 MB
    const size_t QTB  = (size_t)N_NODESC * 96 * sizeof(__hip_bfloat16);   // 9.6 MB
    const size_t CNT  = ((size_t)N_NODESC * sizeof(int) + 255) & ~255ull; // 200 KB
    const size_t EDG  = (size_t)N_EDGESC * sizeof(int2);                  // 12.8 MB
    const size_t WBT2 = ((size_t)192 * 64 * 2 + 255) & ~255ull;
    const size_t W1CG = ((size_t)96 * 64 * 2 + 255) & ~255ull;
    const size_t W2TS = ((size_t)96 * 96 * 2 + 255) & ~255ull;
    const size_t SORT_WS = SREC + QTB + 2 * CNT + EDG + WBT2 + W1CG + W2TS + 256;

    const size_t TBL = (size_t)N_NODESC * HID * sizeof(__hip_bfloat16);   // 9.6 MB
    const bool big = ws_size >= 4 * TBL + 16;
    const bool srt = ws_size >= SORT_WS;

    if (srt) {
        char* ws = (char*)d_ws;
        __hip_bfloat16* SrcRec = (__hip_bfloat16*)(ws);
        __hip_bfloat16* Qt     = (__hip_bfloat16*)(ws + SREC);
        int* counts            = (int*)(ws + SREC + QTB);
        int* cur               = (int*)(ws + SREC + QTB + CNT);
        int2* edges            = (int2*)(ws + SREC + QTB + 2 * CNT);
        __hip_bfloat16* WbT2   = (__hip_bfloat16*)(ws + SREC + QTB + 2 * CNT + EDG);
        __hip_bfloat16* W1cgT  = (__hip_bfloat16*)(ws + SREC + QTB + 2 * CNT + EDG + WBT2);
        __hip_bfloat16* W2Tb   = (__hip_bfloat16*)(ws + SREC + QTB + 2 * CNT + EDG + WBT2 + W1CG);
        int* flag              = (int*)(ws + SREC + QTB + 2 * CNT + EDG + WBT2 + W1CG + W2TS);

        detect_zero<<<(N_NODESC + 255) / 256, 256, 0, stream>>>(ei, flag, counts);
        fused_init<<<(N_NODESC * (SDIM + VDIM) + 255) / 256, 256, 0, stream>>>(
            hs, hv, out, counts, W1, W2, SrcRec, WbT2, W1cgT, W2Tb, ei, flag);
        scan_kernel<<<1, 1024, 0, stream>>>(counts, cur);
        scatter_kernel<<<N_EDGESC / 256, 256, 0, stream>>>(ei, flag, cur, edges);
        node_precompute_mfma<<<(N_NODESC + 63) / 64, 256, 0, stream>>>(
            hs, WbT2, b1, SrcRec, Qt);
        edge_kernel_sorted<<<GRID_E, 256, 0, stream>>>(edges, pos, ori, W2Tb, b2,
                                                       SrcRec, Qt, W1cgT, out);
    } else if (big) {
        char* ws = (char*)d_ws;
        __hip_bfloat16* Pp = (__hip_bfloat16*)(ws);
        __hip_bfloat16* Qt = (__hip_bfloat16*)(ws + TBL);
        __hip_bfloat16* Ut = (__hip_bfloat16*)(ws + 2 * TBL);
        __hip_bfloat16* Vt = (__hip_bfloat16*)(ws + 3 * TBL);
        int* flag = (int*)(ws + 4 * TBL);
        init_out<<<(N_NODESC * (SDIM + VDIM) + 255) / 256, 256, 0, stream>>>(hs, hv, out);
        detect_kernel<<<1, 64, 0, stream>>>(ei, flag);
        node_precompute<<<N_NODESC, 128, 0, stream>>>(hs, hv, W1, b1, Pp, Qt, Ut, Vt);
        edge_kernel<<<2500, 256, 0, stream>>>(ei, pos, ori, W1, W2, b2,
                                              Pp, Qt, Ut, Vt, flag, out);
    } else {
        int* flag = (int*)d_ws;
        init_out<<<(N_NODESC * (SDIM + VDIM) + 255) / 256, 256, 0, stream>>>(hs, hv, out);
        detect_kernel<<<1, 64, 0, stream>>>(ei, flag);
        edge_fallback<<<N_EDGESC, 192, 0, stream>>>(ei, hs, hv, pos, ori, W1, b1,
                                                    W2, b2, flag, out);
    }
}

// Round 8
// 589.480 us; speedup vs baseline: 1.3329x; 1.0299x over previous
//
#include <hip/hip_runtime.h>
#include <hip/hip_bf16.h>

#define N_NODESC 50000
#define N_EDGESC 1600000
#define SDIM 64
#define VDIM 32
#define HID 96
#define IN_DIMC 163

#define GRID_E 6250
#define TPB_E 4            // tiles per block (25000 tiles / 6250 blocks)
#define NXCD 8
#define XQ (GRID_E / NXCD) // 781
#define XR (GRID_E % NXCD) // 2

typedef float f32x4 __attribute__((ext_vector_type(4)));
typedef short s16x8 __attribute__((ext_vector_type(8)));

__device__ __forceinline__ float bf2f(__hip_bfloat16 x) { return __bfloat162float(x); }
__device__ __forceinline__ __hip_bfloat16 f2bf(float x) { return __float2bfloat16(x); }
__device__ __forceinline__ float bfbits2f(short b) {
    unsigned u = ((unsigned)(unsigned short)b) << 16;
    return __builtin_bit_cast(float, u);
}
__device__ __forceinline__ short f2bfbits(float x) {
    __hip_bfloat16 h = __float2bfloat16(x);
    return *(const short*)&h;
}

// ---------------------------------------------------------------------------
// Detect int64 layout + zero the histogram counters (merged; one launch).
__global__ void detect_zero(const int* ei, int* flag, int* __restrict__ counts) {
    int i = blockIdx.x * blockDim.x + threadIdx.x;
    if (i < N_NODESC) counts[i] = 0;
    if (i == 0) {
        int z = 1;
        for (int k = 0; k < 64; ++k) {
            if (ei[2 * k + 1] != 0) { z = 0; break; }
        }
        *flag = z;  // 1 -> int64 layout
    }
}

// ---------------------------------------------------------------------------
// Fused one-shot prep (vectorized; grid = 6250 x 256 = 1.6M threads, sized by
// the histogram job). Jobs: out-init (float4), SrcRec.hv (8-wide), weight
// repacks, dst histogram.
__global__ void fused_init(const float* __restrict__ hs, const float* __restrict__ hv,
                           float* __restrict__ out, int* __restrict__ counts,
                           const float* __restrict__ W1, const float* __restrict__ W2,
                           __hip_bfloat16* __restrict__ SrcRec,
                           __hip_bfloat16* __restrict__ WbT2,
                           __hip_bfloat16* __restrict__ W1cgT,
                           __hip_bfloat16* __restrict__ W2Tb,
                           const int* __restrict__ ei, const int* __restrict__ flag64) {
    int i = blockIdx.x * blockDim.x + threadIdx.x;  // 0..1.6M-1
    // out = residual (hs | hv), float4-wide
    if (i < N_NODESC * (SDIM + VDIM) / 4) {
        const int HS4 = N_NODESC * SDIM / 4;  // 800000
        float4 v = (i < HS4) ? ((const float4*)hs)[i] : ((const float4*)hv)[i - HS4];
        ((float4*)out)[i] = v;
    }
    // SrcRec[n][96..128) = bf16(hv[n]), 8 elems/thread
    if (i < N_NODESC * VDIM / 8) {
        int n = i >> 2, c = i & 3;
        const float4* hv4 = (const float4*)hv;
        float4 a = hv4[n * 8 + c * 2];
        float4 bq = hv4[n * 8 + c * 2 + 1];
        s16x8 o;
        o[0] = f2bfbits(a.x);  o[1] = f2bfbits(a.y);
        o[2] = f2bfbits(a.z);  o[3] = f2bfbits(a.w);
        o[4] = f2bfbits(bq.x); o[5] = f2bfbits(bq.y);
        o[6] = f2bfbits(bq.z); o[7] = f2bfbits(bq.w);
        *(s16x8*)&SrcRec[n * 128 + 96 + c * 8] = o;
    }
    // WbT2 [192][64]: rows 0-95 = W1a^T (P), 96-191 = W1b^T (Q)
    if (i < 192 * 64) {
        int n = i >> 6, k = i & 63;
        float val = (n < 96) ? W1[k * HID + n] : W1[(64 + k) * HID + (n - 96)];
        WbT2[i] = f2bf(val);
    }
    // W1cgT [96][64]: cols 0-31 = W1c^T, 32-34 = geo rows, rest 0
    if (i < 96 * 64) {
        int n = i >> 6, k = i & 63;
        float val = 0.f;
        if (k < 32) val = W1[(128 + k) * HID + n];
        else if (k < 35) val = W1[(160 + (k - 32)) * HID + n];
        W1cgT[i] = f2bf(val);
    }
    // W2Tb [96][96] = W2^T
    if (i < 96 * 96) {
        int n = i / 96, k = i - (i / 96) * 96;
        W2Tb[i] = f2bf(W2[k * HID + n]);
    }
    // dst histogram (every thread owns one edge; grid == N_EDGESC threads)
    {
        int dN;
        if (*flag64) dN = (int)((const long long*)ei)[N_EDGESC + i];
        else dN = ei[N_EDGESC + i];
        atomicAdd(&counts[dN], 1);
    }
}

// ---------------------------------------------------------------------------
// MFMA node precompute (K=64): [P|Q] = hs_bf16 @ [W1a|W1b]; P (+b1) ->
// SrcRec[n][0:96), Q -> Qt[n][:]. Output staged in LDS, stored coalesced.
__global__ __launch_bounds__(256, 2) void node_precompute_mfma(
    const float* __restrict__ hs, const __hip_bfloat16* __restrict__ WbT2,
    const float* __restrict__ b1,
    __hip_bfloat16* __restrict__ SrcRec, __hip_bfloat16* __restrict__ Qt) {
    __shared__ __hip_bfloat16 sA[64][72];
    __shared__ __hip_bfloat16 sOut[64][200];  // 192 used
    const int t = threadIdx.x;
    const int lane = t & 63;
    const int w = t >> 6;
    const int m16 = lane & 15;
    const int q = lane >> 4;
    const int nb = blockIdx.x * 64;

    for (int idx = t; idx < 64 * 64; idx += 256) {
        int node = idx >> 6, f = idx & 63;
        int g = nb + node;
        sA[node][f] = f2bf(g < N_NODESC ? hs[g * SDIM + f] : 0.f);
    }
    __syncthreads();

    s16x8 bfr[3][2];
    float b1v[3];
    for (int nt = 0; nt < 3; ++nt) {
        int n_out = w * 48 + nt * 16 + m16;
        for (int kt = 0; kt < 2; ++kt)
            bfr[nt][kt] = *(const s16x8*)&WbT2[n_out * 64 + kt * 32 + q * 8];
        b1v[nt] = (n_out < 96) ? b1[n_out] : 0.f;
    }

    for (int ms = 0; ms < 4; ++ms) {
        s16x8 afr[2];
        for (int kt = 0; kt < 2; ++kt)
            afr[kt] = *(const s16x8*)&sA[ms * 16 + m16][kt * 32 + q * 8];
        f32x4 acc[3];
        for (int nt = 0; nt < 3; ++nt) acc[nt] = (f32x4){0.f, 0.f, 0.f, 0.f};
        for (int nt = 0; nt < 3; ++nt)
            for (int kt = 0; kt < 2; ++kt)
                acc[nt] = __builtin_amdgcn_mfma_f32_16x16x32_bf16(
                    afr[kt], bfr[nt][kt], acc[nt], 0, 0, 0);
        for (int nt = 0; nt < 3; ++nt) {
            int n_out = w * 48 + nt * 16 + m16;
            for (int r = 0; r < 4; ++r)
                sOut[ms * 16 + q * 4 + r][n_out] = f2bf(acc[nt][r] + b1v[nt]);
        }
    }
    __syncthreads();

    for (int idx = t; idx < 64 * 12; idx += 256) {
        int node = idx / 12, ch = idx - (idx / 12) * 12;
        int g = nb + node;
        if (g < N_NODESC)
            *(s16x8*)&SrcRec[g * 128 + ch * 8] = *(const s16x8*)&sOut[node][ch * 8];
    }
    for (int idx = t; idx < 64 * 12; idx += 256) {
        int node = idx / 12, ch = idx - (idx / 12) * 12;
        int g = nb + node;
        if (g < N_NODESC)
            *(s16x8*)&Qt[g * 96 + ch * 8] = *(const s16x8*)&sOut[node][96 + ch * 8];
    }
}

// ---------------------------------------------------------------------------
__global__ __launch_bounds__(1024) void scan_kernel(
    const int* __restrict__ counts, int* __restrict__ cur) {
    __shared__ int part[1024];
    const int t = threadIdx.x;
    const int CH = (N_NODESC + 1023) / 1024;  // 49
    int lo = t * CH;
    int hi = lo + CH; if (hi > N_NODESC) hi = N_NODESC;
    int s = 0;
    for (int i = lo; i < hi; ++i) s += counts[i];
    part[t] = s;
    __syncthreads();
    for (int d = 1; d < 1024; d <<= 1) {
        int v = (t >= d) ? part[t - d] : 0;
        __syncthreads();
        part[t] += v;
        __syncthreads();
    }
    int run = (t == 0) ? 0 : part[t - 1];
    for (int i = lo; i < hi; ++i) {
        int c = counts[i];
        cur[i] = run;
        run += c;
    }
}

__global__ __launch_bounds__(256) void scatter_kernel(
    const int* __restrict__ ei, const int* __restrict__ flag64,
    int* __restrict__ cur, int2* __restrict__ edges) {
    int e = blockIdx.x * blockDim.x + threadIdx.x;
    if (e >= N_EDGESC) return;
    int sN, dN;
    if (*flag64) {
        const long long* e64 = (const long long*)ei;
        sN = (int)e64[e]; dN = (int)e64[N_EDGESC + e];
    } else { sN = ei[e]; dN = ei[N_EDGESC + e]; }
    int p = atomicAdd(&cur[dN], 1);
    edges[p] = make_int2(sN, dN);
}

// ---------------------------------------------------------------------------
// Main edge kernel (dst-sorted, chunked+XCD-swizzled, cross-tile prefetch).
// A-frag-aligned phase-1b: thread (w,q,m16) computes silu(P+Q+V) for exactly
// the h-values its layer-2 A-fragment needs (edge eM=w*16+m16, j=kt*32+q*8),
// so h goes straight to registers — no hA LDS round-trip. All LDS rows in
// steps 1-8 are wave-private (hVG, s_vf, meta), so only TWO block barriers
// per tile remain: before and after the cross-wave segment reduction.
__global__ __launch_bounds__(256, 3) void edge_kernel_sorted(
    const int2* __restrict__ edges,
    const float* __restrict__ pos, const float* __restrict__ ori,
    const __hip_bfloat16* __restrict__ W2Tb, const float* __restrict__ b2,
    const __hip_bfloat16* __restrict__ SrcRec, const __hip_bfloat16* __restrict__ Qt,
    const __hip_bfloat16* __restrict__ W1cgT,
    float* __restrict__ out) {
    __shared__ int s_srcM[2][64], s_dstM[2][64];
    __shared__ alignas(16) __hip_bfloat16 hVG[64][72];    // [0:32) rot-hv, [32:64) geo
    __shared__ alignas(16) __hip_bfloat16 s_vf[64][104];  // vec+geo contrib / msg
    __shared__ alignas(16) short sW2f[18 * 64 * 8];       // W2 frags, lane-packed
    __shared__ int s_segstart[66];

    const int t = threadIdx.x;
    const int lane = t & 63;
    const int w = t >> 6;        // wave id 0..3
    const int m16 = lane & 15;
    const int q = lane >> 4;
    const int el = t >> 2;       // edge-role: edge index 0..63 (own-wave rows)
    const int quad = t & 3;      // edge-role: quad 0..3
    const int eM = w * 16 + m16; // MFMA-role: A-fragment edge (own-wave row)

    // W2 fragments -> LDS, packed by (frag, lane): ds_read_b128 at lane*16B.
    if (w == 0) {
        for (int f = 0; f < 18; ++f) {
            int nt = f / 3, kt = f - (f / 3) * 3;
            *(s16x8*)&sW2f[(f * 64 + lane) * 8] =
                *(const s16x8*)&W2Tb[(nt * 16 + m16) * 96 + kt * 32 + q * 8];
        }
    }
    // W1cg fragments (K=64 -> 2 per nt) in registers.
    s16x8 bfrC[6][2];
    #pragma unroll
    for (int nt = 0; nt < 6; ++nt)
        #pragma unroll
        for (int kt = 0; kt < 2; ++kt)
            bfrC[nt][kt] = *(const s16x8*)&W1cgT[(nt * 16 + m16) * 64 + kt * 32 + q * 8];
    float b2v[6];
    #pragma unroll
    for (int nt = 0; nt < 6; ++nt) b2v[nt] = b2[nt * 16 + m16];

    // Chunked, XCD-swizzled tile range.
    int b = blockIdx.x;
    int xcd = b & 7, bi = b >> 3;
    int c = (xcd < XR) ? (xcd * (XQ + 1) + bi)
                       : (XR * (XQ + 1) + (xcd - XR) * XQ + bi);
    const int tile0 = c * TPB_E;

    // ---- prologue: stage tile 0 meta, prefetch tile 1's edge ids ----
    int2 edT1;            // edges for tile tl+1 (edge-role)
    s16x8 hvvT;           // raw hv gather for current tile
    float rcT, rsT;       // rotation coeffs (current tile)
    float gdT, gcgT, gsgT;// geo features (current tile)
    {
        int2 edT = edges[tile0 * 64 + el];
        edT1 = edges[(tile0 + 1) * 64 + el];
        hvvT = *(const s16x8*)&SrcRec[edT.x * 128 + 96 + quad * 8];
        int sN = edT.x, dN = edT.y;
        float ca, sa, cb, sb;
        __sincosf(2.0f * ori[dN], &sa, &ca);
        __sincosf(2.0f * ori[sN], &sb, &cb);
        rcT = cb * ca + sb * sa;
        rsT = sb * ca - cb * sa;
        float dx = pos[2 * sN] - pos[2 * dN];
        float dy = pos[2 * sN + 1] - pos[2 * dN + 1];
        float d2 = dx * dx + dy * dy;
        gdT = sqrtf(d2) + 1e-6f;
        float c2f, s2f;
        if (d2 > 0.f) {
            float inv = 1.0f / d2;
            c2f = (dx * dx - dy * dy) * inv;
            s2f = 2.0f * dx * dy * inv;
        } else { c2f = 1.0f; s2f = 0.0f; }
        gcgT = c2f * ca + s2f * sa;
        gsgT = s2f * ca - c2f * sa;
        if (quad == 0) { s_srcM[0][el] = sN; s_dstM[0][el] = dN; }
    }
    __syncthreads();
    // Issue P/Q gathers for tile 0 (A-frag-aligned: edge eM, chunks kt*32+q*8).
    s16x8 pqP[3], pqQ[3];
    {
        int sN = s_srcM[0][eM], dN = s_dstM[0][eM];
        #pragma unroll
        for (int kt = 0; kt < 3; ++kt) {
            pqP[kt] = *(const s16x8*)&SrcRec[sN * 128 + kt * 32 + q * 8];
            pqQ[kt] = *(const s16x8*)&Qt[dN * 96 + kt * 32 + q * 8];
        }
    }

    int cur = 0;
    for (int tl = 0; tl < TPB_E; ++tl) {
        const int nx = cur ^ 1;
        const int tlN2 = (tl + 2 < TPB_E) ? tl + 2 : TPB_E - 1;

        // 1. rotate hv(T) + geo -> hVG rows (own-wave; in-order LDS)
        {
            s16x8 rv;
            #pragma unroll
            for (int p2 = 0; p2 < 4; ++p2) {
                float x = bfbits2f(hvvT[2 * p2]), y = bfbits2f(hvvT[2 * p2 + 1]);
                rv[2 * p2]     = f2bfbits(rcT * x - rsT * y);
                rv[2 * p2 + 1] = f2bfbits(rsT * x + rcT * y);
            }
            *(s16x8*)&hVG[el][quad * 8] = rv;
            s16x8 up = (s16x8){0, 0, 0, 0, 0, 0, 0, 0};
            if (quad == 0) {
                up[0] = f2bfbits(gdT); up[1] = f2bfbits(gcgT); up[2] = f2bfbits(gsgT);
            }
            *(s16x8*)&hVG[el][32 + quad * 8] = up;
        }
        // 2/3. prefetch edges(T+2) and hv(T+1) — long-latency, used next iter
        int2 edT2 = edges[(tile0 + tlN2) * 64 + el];
        s16x8 hvvN = *(const s16x8*)&SrcRec[edT1.x * 128 + 96 + quad * 8];
        // 4. vec+geo via K=64 MFMA -> s_vf rows (own-wave)
        {
            s16x8 afr0 = *(const s16x8*)&hVG[eM][q * 8];
            s16x8 afr1 = *(const s16x8*)&hVG[eM][32 + q * 8];
            #pragma unroll
            for (int nt = 0; nt < 6; ++nt) {
                f32x4 a1 = __builtin_amdgcn_mfma_f32_16x16x32_bf16(
                    afr0, bfrC[nt][0], (f32x4){0.f, 0.f, 0.f, 0.f}, 0, 0, 0);
                a1 = __builtin_amdgcn_mfma_f32_16x16x32_bf16(
                    afr1, bfrC[nt][1], a1, 0, 0, 0);
                int u = nt * 16 + m16;
                #pragma unroll
                for (int r = 0; r < 4; ++r)
                    s_vf[w * 16 + q * 4 + r][u] = f2bf(a1[r]);
            }
        }
        // 5. meta + rotation + geo for T+1 -> regs + meta[nx] (own-wave rows)
        float rcN, rsN, gdN, gcgN, gsgN;
        {
            int sN = edT1.x, dN = edT1.y;
            float ca, sa, cb, sb;
            __sincosf(2.0f * ori[dN], &sa, &ca);
            __sincosf(2.0f * ori[sN], &sb, &cb);
            rcN = cb * ca + sb * sa;
            rsN = sb * ca - cb * sa;
            float dx = pos[2 * sN] - pos[2 * dN];
            float dy = pos[2 * sN + 1] - pos[2 * dN + 1];
            float d2 = dx * dx + dy * dy;
            gdN = sqrtf(d2) + 1e-6f;
            float c2f, s2f;
            if (d2 > 0.f) {
                float inv = 1.0f / d2;
                c2f = (dx * dx - dy * dy) * inv;
                s2f = 2.0f * dx * dy * inv;
            } else { c2f = 1.0f; s2f = 0.0f; }
            gcgN = c2f * ca + s2f * sa;
            gsgN = s2f * ca - c2f * sa;
            if (quad == 0) { s_srcM[nx][el] = sN; s_dstM[nx][el] = dN; }
        }

        // 6. phase-1b: silu(P + Q + V) straight into A-fragments (no barrier:
        //    s_vf rows w*16..w*16+15 were written by this wave in step 4)
        s16x8 afr[3];
        #pragma unroll
        for (int kt = 0; kt < 3; ++kt) {
            int j = kt * 32 + q * 8;
            s16x8 Vv = *(const s16x8*)&s_vf[eM][j];
            s16x8 hb;
            #pragma unroll
            for (int k2 = 0; k2 < 8; ++k2) {
                float pre = bfbits2f(pqP[kt][k2]) + bfbits2f(pqQ[kt][k2])
                          + bfbits2f(Vv[k2]);
                float h = pre / (1.0f + __expf(-pre));  // silu
                hb[k2] = f2bfbits(h);
            }
            afr[kt] = hb;
        }
        // 7. prefetch P/Q for T+1 (meta[nx] written by own wave in step 5)
        {
            int sN = s_srcM[nx][eM], dN = s_dstM[nx][eM];
            #pragma unroll
            for (int kt = 0; kt < 3; ++kt) {
                pqP[kt] = *(const s16x8*)&SrcRec[sN * 128 + kt * 32 + q * 8];
                pqQ[kt] = *(const s16x8*)&Qt[dN * 96 + kt * 32 + q * 8];
            }
        }
        // 8. layer-2 MFMA (B frags from LDS) -> msg overwrites s_vf (own-wave;
        //    LDS in-order guarantees step-6 reads complete first)
        {
            f32x4 acc[6];
            #pragma unroll
            for (int nt = 0; nt < 6; ++nt) acc[nt] = (f32x4){0.f, 0.f, 0.f, 0.f};
            #pragma unroll
            for (int nt = 0; nt < 6; ++nt)
                #pragma unroll
                for (int kt = 0; kt < 3; ++kt) {
                    s16x8 bf = *(const s16x8*)&sW2f[((nt * 3 + kt) * 64 + lane) * 8];
                    acc[nt] = __builtin_amdgcn_mfma_f32_16x16x32_bf16(
                        afr[kt], bf, acc[nt], 0, 0, 0);
                }
            #pragma unroll
            for (int nt = 0; nt < 6; ++nt) {
                int u = nt * 16 + m16;
                float bb = b2v[nt];
                #pragma unroll
                for (int r = 0; r < 4; ++r)
                    s_vf[w * 16 + q * 4 + r][u] = f2bf(acc[nt][r] + bb);
            }
        }
        __syncthreads();  // [B1] all waves' msg + meta visible

        // 9. segment ballot (redundant per wave) + reduce, one atomic per
        //    (segment, unit)
        {
            int dl = s_dstM[cur][lane];
            int dp = (lane > 0) ? s_dstM[cur][lane - 1] : -1;
            bool bnd = (lane > 0) && (dl != dp);
            unsigned long long mask = __ballot(bnd);
            int nseg = (int)__popcll(mask) + 1;
            if (bnd) s_segstart[__popcll(mask & (~0ull >> (63 - lane)))] = lane;
            if (lane == 0) s_segstart[0] = 0;

            for (int idx = t; idx < nseg * HID; idx += 256) {
                int sg = idx / HID;
                int u = idx - sg * HID;
                int e0 = s_segstart[sg];
                int e1 = (sg + 1 < nseg) ? s_segstart[sg + 1] : 64;
                float sum = 0.f;
                for (int e = e0; e < e1; ++e) sum += bf2f(s_vf[e][u]);
                int dN = s_dstM[cur][e0];
                if (u < SDIM) atomicAdd(&out[dN * SDIM + u], sum);
                else atomicAdd(&out[N_NODESC * SDIM + dN * VDIM + (u - SDIM)], sum);
            }
        }

        // 10. rotate pipeline state
        edT1 = edT2; hvvT = hvvN;
        rcT = rcN; rsT = rsN; gdT = gdN; gcgT = gcgN; gsgT = gsgN;
        cur = nx;
        __syncthreads();  // [B2] reduce done before next tile overwrites LDS
    }
}

// ---------------------------------------------------------------------------
// Mid-tier: f32 per-node precompute (4 tables) + unsorted atomic-scatter kernel.
__global__ __launch_bounds__(128) void node_precompute(
    const float* __restrict__ hs, const float* __restrict__ hv,
    const float* __restrict__ W1, const float* __restrict__ b1,
    __hip_bfloat16* __restrict__ Pp, __hip_bfloat16* __restrict__ Qt,
    __hip_bfloat16* __restrict__ Ut, __hip_bfloat16* __restrict__ Vt) {
    int n = blockIdx.x;
    __shared__ float s_hs[SDIM];
    __shared__ float s_hv[VDIM];
    int t = threadIdx.x;
    if (t < 64) s_hs[t] = hs[n * SDIM + t];
    else if (t < 96) s_hv[t - 64] = hv[n * VDIM + (t - 64)];
    __syncthreads();
    if (t < HID) {
        float p = b1[t], qq = 0.f, u = 0.f, v = 0.f;
        for (int k = 0; k < 64; ++k) {
            float x = s_hs[k];
            p += x * W1[k * HID + t];
            qq += x * W1[(64 + k) * HID + t];
        }
        for (int pr = 0; pr < 16; ++pr) {
            float x = s_hv[2 * pr], y = s_hv[2 * pr + 1];
            float wa = W1[(128 + 2 * pr) * HID + t];
            float wb = W1[(128 + 2 * pr + 1) * HID + t];
            u += x * wa + y * wb;
            v += x * wb - y * wa;
        }
        Pp[n * HID + t] = f2bf(p);
        Qt[n * HID + t] = f2bf(qq);
        Ut[n * HID + t] = f2bf(u);
        Vt[n * HID + t] = f2bf(v);
    }
}

__global__ void init_out(const float* __restrict__ hs, const float* __restrict__ hv,
                         float* __restrict__ out) {
    int i = blockIdx.x * blockDim.x + threadIdx.x;
    if (i >= N_NODESC * (SDIM + VDIM)) return;
    out[i] = (i < N_NODESC * SDIM) ? hs[i] : hv[i - N_NODESC * SDIM];
}

__global__ void detect_kernel(const int* ei, int* flag) {
    if (blockIdx.x == 0 && threadIdx.x == 0) {
        int z = 1;
        for (int k = 0; k < 64; ++k) {
            if (ei[2 * k + 1] != 0) { z = 0; break; }
        }
        *flag = z;
    }
}

__global__ __launch_bounds__(256) void edge_kernel(
    const int* __restrict__ ei, const float* __restrict__ pos,
    const float* __restrict__ ori, const float* __restrict__ W1,
    const float* __restrict__ W2, const float* __restrict__ b2,
    const __hip_bfloat16* __restrict__ Pp, const __hip_bfloat16* __restrict__ Qt,
    const __hip_bfloat16* __restrict__ Ut, const __hip_bfloat16* __restrict__ Vt,
    const int* __restrict__ flag64, float* __restrict__ out) {
    __shared__ int s_src[64], s_dst[64];
    __shared__ float s_c[64], s_s[64], s_d[64], s_cg[64], s_sg[64];
    __shared__ float s_w1d[3][HID];
    __shared__ __hip_bfloat16 hA[64][104];
    __shared__ __hip_bfloat16 W2T[HID][104];

    const int t = threadIdx.x;
    const int lane = t & 63;
    const int w = t >> 6;
    const int m16 = lane & 15;
    const int q = lane >> 4;

    for (int idx = t; idx < HID * HID; idx += 256) {
        int k = idx / HID;
        int n = idx - k * HID;
        W2T[n][k] = f2bf(W2[idx]);
    }
    for (int idx = t; idx < 3 * HID; idx += 256) {
        int r = idx / HID, j = idx - r * HID;
        s_w1d[r][j] = W1[(160 + r) * HID + j];
    }
    __syncthreads();

    s16x8 bfr[6][3];
    for (int nt = 0; nt < 6; ++nt)
        for (int kt = 0; kt < 3; ++kt)
            bfr[nt][kt] = *(const s16x8*)&W2T[nt * 16 + m16][kt * 32 + q * 8];
    float b2v[6];
    for (int nt = 0; nt < 6; ++nt) b2v[nt] = b2[nt * 16 + m16];

    const bool i64 = (*flag64 != 0);
    const long long* ei64 = (const long long*)ei;

    for (int tile = blockIdx.x; tile < N_EDGESC / 64; tile += gridDim.x) {
        __syncthreads();

        if (t < 64) {
            int e = tile * 64 + t;
            int sN, dN;
            if (i64) { sN = (int)ei64[e]; dN = (int)ei64[N_EDGESC + e]; }
            else     { sN = ei[e];        dN = ei[N_EDGESC + e]; }
            s_src[t] = sN; s_dst[t] = dN;
            float ca, sa, cb, sb;
            __sincosf(2.0f * ori[dN], &sa, &ca);
            __sincosf(2.0f * ori[sN], &sb, &cb);
            s_c[t] = cb * ca + sb * sa;
            s_s[t] = sb * ca - cb * sa;
            float dx = pos[2 * sN] - pos[2 * dN];
            float dy = pos[2 * sN + 1] - pos[2 * dN + 1];
            float d2 = dx * dx + dy * dy;
            s_d[t] = sqrtf(d2) + 1e-6f;
            float c2f, s2f;
            if (d2 > 0.f) {
                float inv = 1.0f / d2;
                c2f = (dx * dx - dy * dy) * inv;
                s2f = 2.0f * dx * dy * inv;
            } else { c2f = 1.0f; s2f = 0.0f; }
            s_cg[t] = c2f * ca + s2f * sa;
            s_sg[t] = s2f * ca - c2f * sa;
        }
        __syncthreads();

        for (int p = 0; p < 24; ++p) {
            int idx = p * 256 + t;
            int e = idx / HID;
            int j = idx - e * HID;
            int sN = s_src[e], dN = s_dst[e];
            float pre = bf2f(Pp[sN * HID + j]) + bf2f(Qt[dN * HID + j])
                      + s_c[e] * bf2f(Ut[sN * HID + j])
                      + s_s[e] * bf2f(Vt[sN * HID + j])
                      + s_d[e] * s_w1d[0][j] + s_cg[e] * s_w1d[1][j]
                      + s_sg[e] * s_w1d[2][j];
            float h = pre / (1.0f + __expf(-pre));
            hA[e][j] = f2bf(h);
        }
        __syncthreads();

        f32x4 acc[6];
        for (int nt = 0; nt < 6; ++nt) acc[nt] = (f32x4){0.f, 0.f, 0.f, 0.f};
        s16x8 afr[3];
        for (int kt = 0; kt < 3; ++kt)
            afr[kt] = *(const s16x8*)&hA[w * 16 + m16][kt * 32 + q * 8];
        for (int nt = 0; nt < 6; ++nt)
            for (int kt = 0; kt < 3; ++kt)
                acc[nt] = __builtin_amdgcn_mfma_f32_16x16x32_bf16(
                    afr[kt], bfr[nt][kt], acc[nt], 0, 0, 0);

        for (int nt = 0; nt < 6; ++nt) {
            int u = nt * 16 + m16;
            for (int r = 0; r < 4; ++r) {
                int eloc = w * 16 + q * 4 + r;
                int dN = s_dst[eloc];
                float val = acc[nt][r] + b2v[nt];
                if (u < SDIM) atomicAdd(&out[dN * SDIM + u], val);
                else atomicAdd(&out[N_NODESC * SDIM + dN * VDIM + (u - SDIM)], val);
            }
        }
    }
}

// ---------------------------------------------------------------------------
// Fallback (ws too small for tables): fully per-edge, correct but slow.
__global__ __launch_bounds__(192) void edge_fallback(
    const int* __restrict__ ei, const float* __restrict__ hs,
    const float* __restrict__ hv, const float* __restrict__ pos,
    const float* __restrict__ ori, const float* __restrict__ W1,
    const float* __restrict__ b1, const float* __restrict__ W2,
    const float* __restrict__ b2, const int* __restrict__ flag64,
    float* __restrict__ out) {
    __shared__ float s_msg[IN_DIMC];
    __shared__ float s_h[HID];
    int e = blockIdx.x;
    int t = threadIdx.x;
    const bool i64 = (*flag64 != 0);
    int sN, dN;
    if (i64) {
        const long long* e64 = (const long long*)ei;
        sN = (int)e64[e]; dN = (int)e64[N_EDGESC + e];
    } else { sN = ei[e]; dN = ei[N_EDGESC + e]; }

    if (t < IN_DIMC) {
        if (t < 64) s_msg[t] = hs[sN * SDIM + t];
        else if (t < 128) s_msg[t] = hs[dN * SDIM + (t - 64)];
        else {
            float ca, sa, cb, sb;
            __sincosf(2.0f * ori[dN], &sa, &ca);
            __sincosf(2.0f * ori[sN], &sb, &cb);
            float c = cb * ca + sb * sa;
            float s = sb * ca - cb * sa;
            float dx = pos[2 * sN] - pos[2 * dN];
            float dy = pos[2 * sN + 1] - pos[2 * dN + 1];
            float d2 = dx * dx + dy * dy;
            if (t < 160) {
                int pr = (t - 128) >> 1;
                float x = hv[sN * VDIM + 2 * pr], y = hv[sN * VDIM + 2 * pr + 1];
                s_msg[t] = ((t & 1) == 0) ? (c * x - s * y) : (s * x + c * y);
            } else if (t == 160) s_msg[t] = sqrtf(d2) + 1e-6f;
            else {
                float c2f = 1.0f, s2f = 0.0f;
                if (d2 > 0.f) {
                    float inv = 1.0f / d2;
                    c2f = (dx * dx - dy * dy) * inv;
                    s2f = 2.0f * dx * dy * inv;
                }
                s_msg[t] = (t == 161) ? (c2f * ca + s2f * sa) : (s2f * ca - c2f * sa);
            }
        }
    }
    __syncthreads();
    if (t < HID) {
        float a = b1[t];
        for (int k = 0; k < IN_DIMC; ++k) a += s_msg[k] * W1[k * HID + t];
        s_h[t] = a / (1.0f + __expf(-a));
    }
    __syncthreads();
    if (t < HID) {
        float a = b2[t];
        for (int k = 0; k < HID; ++k) a += s_h[k] * W2[k * HID + t];
        if (t < SDIM) atomicAdd(&out[dN * SDIM + t], a);
        else atomicAdd(&out[N_NODESC * SDIM + dN * VDIM + (t - SDIM)], a);
    }
}

// ---------------------------------------------------------------------------
extern "C" void kernel_launch(void* const* d_in, const int* in_sizes, int n_in,
                              void* d_out, int out_size, void* d_ws, size_t ws_size,
                              hipStream_t stream) {
    const float* hs  = (const float*)d_in[0];
    const float* hv  = (const float*)d_in[1];
    const int*   ei  = (const int*)d_in[2];
    const float* pos = (const float*)d_in[3];
    const float* ori = (const float*)d_in[4];
    const float* W1  = (const float*)d_in[5];
    const float* b1  = (const float*)d_in[6];
    const float* W2  = (const float*)d_in[7];
    const float* b2  = (const float*)d_in[8];
    float* out = (float*)d_out;

    // sorted-tier workspace layout (256B-aligned chunks)
    const size_t SREC = (size_t)N_NODESC * 128 * sizeof(__hip_bfloat16);  // 12.8 MB
    const size_t QTB  = (size_t)N_NODESC * 96 * sizeof(__hip_bfloat16);   // 9.6 MB
    const size_t CNT  = ((size_t)N_NODESC * sizeof(int) + 255) & ~255ull; // 200 KB
    const size_t EDG  = (size_t)N_EDGESC * sizeof(int2);                  // 12.8 MB
    const size_t WBT2 = ((size_t)192 * 64 * 2 + 255) & ~255ull;
    const size_t W1CG = ((size_t)96 * 64 * 2 + 255) & ~255ull;
    const size_t W2TS = ((size_t)96 * 96 * 2 + 255) & ~255ull;
    const size_t SORT_WS = SREC + QTB + 2 * CNT + EDG + WBT2 + W1CG + W2TS + 256;

    const size_t TBL = (size_t)N_NODESC * HID * sizeof(__hip_bfloat16);   // 9.6 MB
    const bool big = ws_size >= 4 * TBL + 16;
    const bool srt = ws_size >= SORT_WS;

    if (srt) {
        char* ws = (char*)d_ws;
        __hip_bfloat16* SrcRec = (__hip_bfloat16*)(ws);
        __hip_bfloat16* Qt     = (__hip_bfloat16*)(ws + SREC);
        int* counts            = (int*)(ws + SREC + QTB);
        int* cur               = (int*)(ws + SREC + QTB + CNT);
        int2* edges            = (int2*)(ws + SREC + QTB + 2 * CNT);
        __hip_bfloat16* WbT2   = (__hip_bfloat16*)(ws + SREC + QTB + 2 * CNT + EDG);
        __hip_bfloat16* W1cgT  = (__hip_bfloat16*)(ws + SREC + QTB + 2 * CNT + EDG + WBT2);
        __hip_bfloat16* W2Tb   = (__hip_bfloat16*)(ws + SREC + QTB + 2 * CNT + EDG + WBT2 + W1CG);
        int* flag              = (int*)(ws + SREC + QTB + 2 * CNT + EDG + WBT2 + W1CG + W2TS);

        detect_zero<<<(N_NODESC + 255) / 256, 256, 0, stream>>>(ei, flag, counts);
        fused_init<<<N_EDGESC / 256, 256, 0, stream>>>(
            hs, hv, out, counts, W1, W2, SrcRec, WbT2, W1cgT, W2Tb, ei, flag);
        scan_kernel<<<1, 1024, 0, stream>>>(counts, cur);
        scatter_kernel<<<N_EDGESC / 256, 256, 0, stream>>>(ei, flag, cur, edges);
        node_precompute_mfma<<<(N_NODESC + 63) / 64, 256, 0, stream>>>(
            hs, WbT2, b1, SrcRec, Qt);
        edge_kernel_sorted<<<GRID_E, 256, 0, stream>>>(edges, pos, ori, W2Tb, b2,
                                                       SrcRec, Qt, W1cgT, out);
    } else if (big) {
        char* ws = (char*)d_ws;
        __hip_bfloat16* Pp = (__hip_bfloat16*)(ws);
        __hip_bfloat16* Qt = (__hip_bfloat16*)(ws + TBL);
        __hip_bfloat16* Ut = (__hip_bfloat16*)(ws + 2 * TBL);
        __hip_bfloat16* Vt = (__hip_bfloat16*)(ws + 3 * TBL);
        int* flag = (int*)(ws + 4 * TBL);
        init_out<<<(N_NODESC * (SDIM + VDIM) + 255) / 256, 256, 0, stream>>>(hs, hv, out);
        detect_kernel<<<1, 64, 0, stream>>>(ei, flag);
        node_precompute<<<N_NODESC, 128, 0, stream>>>(hs, hv, W1, b1, Pp, Qt, Ut, Vt);
        edge_kernel<<<2500, 256, 0, stream>>>(ei, pos, ori, W1, W2, b2,
                                              Pp, Qt, Ut, Vt, flag, out);
    } else {
        int* flag = (int*)d_ws;
        init_out<<<(N_NODESC * (SDIM + VDIM) + 255) / 256, 256, 0, stream>>>(hs, hv, out);
        detect_kernel<<<1, 64, 0, stream>>>(ei, flag);
        edge_fallback<<<N_EDGESC, 192, 0, stream>>>(ei, hs, hv, pos, ori, W1, b1,
                                                    W2, b2, flag, out);
    }
}

// Round 9
// 496.635 us; speedup vs baseline: 1.5821x; 1.1869x over previous
//
#include <hip/hip_runtime.h>
#include <hip/hip_bf16.h>

#define N_NODESC 50000
#define N_EDGESC 1600000
#define SDIM 64
#define VDIM 32
#define HID 96
#define IN_DIMC 163

#define GRID_E 6250
#define TPB_E 4            // tiles per block (25000 tiles / 6250 blocks)
#define NXCD 8
#define XQ (GRID_E / NXCD) // 781
#define XR (GRID_E % NXCD) // 2
#define NPRE 782           // precompute blocks in the fused scatter_precompute
#define SCB 196            // scan blocks (50000 / 256 rounded up)

typedef float f32x4 __attribute__((ext_vector_type(4)));
typedef short s16x8 __attribute__((ext_vector_type(8)));

__device__ __forceinline__ float bf2f(__hip_bfloat16 x) { return __bfloat162float(x); }
__device__ __forceinline__ __hip_bfloat16 f2bf(float x) { return __float2bfloat16(x); }
__device__ __forceinline__ float bfbits2f(short b) {
    unsigned u = ((unsigned)(unsigned short)b) << 16;
    return __builtin_bit_cast(float, u);
}
__device__ __forceinline__ short f2bfbits(float x) {
    __hip_bfloat16 h = __float2bfloat16(x);
    return *(const short*)&h;
}

// ---------------------------------------------------------------------------
// Detect int64 layout + zero the histogram counters (merged; one launch).
__global__ void detect_zero(const int* ei, int* flag, int* __restrict__ counts) {
    int i = blockIdx.x * blockDim.x + threadIdx.x;
    if (i < N_NODESC) counts[i] = 0;
    if (i == 0) {
        int z = 1;
        for (int k = 0; k < 64; ++k) {
            if (ei[2 * k + 1] != 0) { z = 0; break; }
        }
        *flag = z;  // 1 -> int64 layout
    }
}

// ---------------------------------------------------------------------------
// Fused one-shot prep (vectorized; grid = 6250 x 256 = 1.6M threads, sized by
// the histogram job). Jobs: out-init (float4), SrcRec.hv (8-wide), weight
// repacks, dst histogram.
__global__ void fused_init(const float* __restrict__ hs, const float* __restrict__ hv,
                           float* __restrict__ out, int* __restrict__ counts,
                           const float* __restrict__ W1, const float* __restrict__ W2,
                           __hip_bfloat16* __restrict__ SrcRec,
                           __hip_bfloat16* __restrict__ WbT2,
                           __hip_bfloat16* __restrict__ W1cgT,
                           __hip_bfloat16* __restrict__ W2Tb,
                           const int* __restrict__ ei, const int* __restrict__ flag64) {
    int i = blockIdx.x * blockDim.x + threadIdx.x;  // 0..1.6M-1
    // out = residual (hs | hv), float4-wide
    if (i < N_NODESC * (SDIM + VDIM) / 4) {
        const int HS4 = N_NODESC * SDIM / 4;  // 800000
        float4 v = (i < HS4) ? ((const float4*)hs)[i] : ((const float4*)hv)[i - HS4];
        ((float4*)out)[i] = v;
    }
    // SrcRec[n][96..128) = bf16(hv[n]), 8 elems/thread
    if (i < N_NODESC * VDIM / 8) {
        int n = i >> 2, c = i & 3;
        const float4* hv4 = (const float4*)hv;
        float4 a = hv4[n * 8 + c * 2];
        float4 bq = hv4[n * 8 + c * 2 + 1];
        s16x8 o;
        o[0] = f2bfbits(a.x);  o[1] = f2bfbits(a.y);
        o[2] = f2bfbits(a.z);  o[3] = f2bfbits(a.w);
        o[4] = f2bfbits(bq.x); o[5] = f2bfbits(bq.y);
        o[6] = f2bfbits(bq.z); o[7] = f2bfbits(bq.w);
        *(s16x8*)&SrcRec[n * 128 + 96 + c * 8] = o;
    }
    // WbT2 [192][64]: rows 0-95 = W1a^T (P), 96-191 = W1b^T (Q)
    if (i < 192 * 64) {
        int n = i >> 6, k = i & 63;
        float val = (n < 96) ? W1[k * HID + n] : W1[(64 + k) * HID + (n - 96)];
        WbT2[i] = f2bf(val);
    }
    // W1cgT [96][64]: cols 0-31 = W1c^T, 32-34 = geo rows, rest 0
    if (i < 96 * 64) {
        int n = i >> 6, k = i & 63;
        float val = 0.f;
        if (k < 32) val = W1[(128 + k) * HID + n];
        else if (k < 35) val = W1[(160 + (k - 32)) * HID + n];
        W1cgT[i] = f2bf(val);
    }
    // W2Tb [96][96] = W2^T
    if (i < 96 * 96) {
        int n = i / 96, k = i - (i / 96) * 96;
        W2Tb[i] = f2bf(W2[k * HID + n]);
    }
    // dst histogram (every thread owns one edge; grid == N_EDGESC threads)
    {
        int dN;
        if (*flag64) dN = (int)((const long long*)ei)[N_EDGESC + i];
        else dN = ei[N_EDGESC + i];
        atomicAdd(&counts[dN], 1);
    }
}

// ---------------------------------------------------------------------------
// Parallel 3-phase exclusive scan over counts[50000] -> cur.
__global__ __launch_bounds__(256) void scan_partials(
    const int* __restrict__ counts, int* __restrict__ cur, int* __restrict__ bsum) {
    __shared__ int sc[256];
    const int b = blockIdx.x, t = threadIdx.x;
    const int i = b * 256 + t;
    int val = (i < N_NODESC) ? counts[i] : 0;
    sc[t] = val;
    __syncthreads();
    for (int d = 1; d < 256; d <<= 1) {
        int v = (t >= d) ? sc[t - d] : 0;
        __syncthreads();
        sc[t] += v;
        __syncthreads();
    }
    if (i < N_NODESC) cur[i] = sc[t] - val;  // exclusive within block
    if (t == 255) bsum[b] = sc[255];
}

__global__ __launch_bounds__(256) void scan_bsums(
    const int* __restrict__ bsum, int* __restrict__ boff) {
    __shared__ int sc[256];
    const int t = threadIdx.x;
    int val = (t < SCB) ? bsum[t] : 0;
    sc[t] = val;
    __syncthreads();
    for (int d = 1; d < 256; d <<= 1) {
        int v = (t >= d) ? sc[t - d] : 0;
        __syncthreads();
        sc[t] += v;
        __syncthreads();
    }
    if (t < SCB) boff[t] = sc[t] - val;  // exclusive block offsets
}

__global__ __launch_bounds__(256) void scan_apply(
    int* __restrict__ cur, const int* __restrict__ boff) {
    const int i = blockIdx.x * 256 + threadIdx.x;
    if (i < N_NODESC) cur[i] += boff[blockIdx.x];
}

// ---------------------------------------------------------------------------
// Fused scatter + MFMA node-precompute (independent jobs, one launch so the
// MFMA-bound precompute overlaps the atomic/latency-bound scatter).
// Blocks [0, NPRE): precompute 64 nodes each; blocks [NPRE, NPRE+6250): scatter.
__global__ __launch_bounds__(256, 2) void scatter_precompute(
    const int* __restrict__ ei, const int* __restrict__ flag64,
    int* __restrict__ cur, int2* __restrict__ edges,
    const float* __restrict__ hs, const __hip_bfloat16* __restrict__ WbT2,
    const float* __restrict__ b1,
    __hip_bfloat16* __restrict__ SrcRec, __hip_bfloat16* __restrict__ Qt) {
    __shared__ __hip_bfloat16 sA[64][72];
    __shared__ __hip_bfloat16 sOut[64][200];  // 192 used
    const int blk = blockIdx.x;
    const int t = threadIdx.x;

    if (blk >= NPRE) {
        // ---- scatter role ----
        int e = (blk - NPRE) * 256 + t;   // grid sized so e < N_EDGESC
        int sN, dN;
        if (*flag64) {
            const long long* e64 = (const long long*)ei;
            sN = (int)e64[e]; dN = (int)e64[N_EDGESC + e];
        } else { sN = ei[e]; dN = ei[N_EDGESC + e]; }
        int p = atomicAdd(&cur[dN], 1);
        edges[p] = make_int2(sN, dN);
        return;
    }

    // ---- precompute role: [P|Q] = hs_bf16 @ [W1a|W1b], staged + coalesced ----
    const int lane = t & 63;
    const int w = t >> 6;
    const int m16 = lane & 15;
    const int q = lane >> 4;
    const int nb = blk * 64;

    for (int idx = t; idx < 64 * 64; idx += 256) {
        int node = idx >> 6, f = idx & 63;
        int g = nb + node;
        sA[node][f] = f2bf(g < N_NODESC ? hs[g * SDIM + f] : 0.f);
    }
    __syncthreads();

    s16x8 bfr[3][2];
    float b1v[3];
    for (int nt = 0; nt < 3; ++nt) {
        int n_out = w * 48 + nt * 16 + m16;
        for (int kt = 0; kt < 2; ++kt)
            bfr[nt][kt] = *(const s16x8*)&WbT2[n_out * 64 + kt * 32 + q * 8];
        b1v[nt] = (n_out < 96) ? b1[n_out] : 0.f;
    }

    for (int ms = 0; ms < 4; ++ms) {
        s16x8 afr[2];
        for (int kt = 0; kt < 2; ++kt)
            afr[kt] = *(const s16x8*)&sA[ms * 16 + m16][kt * 32 + q * 8];
        f32x4 acc[3];
        for (int nt = 0; nt < 3; ++nt) acc[nt] = (f32x4){0.f, 0.f, 0.f, 0.f};
        for (int nt = 0; nt < 3; ++nt)
            for (int kt = 0; kt < 2; ++kt)
                acc[nt] = __builtin_amdgcn_mfma_f32_16x16x32_bf16(
                    afr[kt], bfr[nt][kt], acc[nt], 0, 0, 0);
        for (int nt = 0; nt < 3; ++nt) {
            int n_out = w * 48 + nt * 16 + m16;
            for (int r = 0; r < 4; ++r)
                sOut[ms * 16 + q * 4 + r][n_out] = f2bf(acc[nt][r] + b1v[nt]);
        }
    }
    __syncthreads();

    for (int idx = t; idx < 64 * 12; idx += 256) {
        int node = idx / 12, ch = idx - (idx / 12) * 12;
        int g = nb + node;
        if (g < N_NODESC)
            *(s16x8*)&SrcRec[g * 128 + ch * 8] = *(const s16x8*)&sOut[node][ch * 8];
    }
    for (int idx = t; idx < 64 * 12; idx += 256) {
        int node = idx / 12, ch = idx - (idx / 12) * 12;
        int g = nb + node;
        if (g < N_NODESC)
            *(s16x8*)&Qt[g * 96 + ch * 8] = *(const s16x8*)&sOut[node][96 + ch * 8];
    }
}

// ---------------------------------------------------------------------------
// Main edge kernel (dst-sorted, chunked+XCD-swizzled, cross-tile prefetch).
// A-frag-aligned phase-1b; silu via fast rcp (output is bf16-quantized, so
// v_rcp_f32's ~2^-22 rel-err is invisible). Two block barriers per tile.
__global__ __launch_bounds__(256, 3) void edge_kernel_sorted(
    const int2* __restrict__ edges,
    const float* __restrict__ pos, const float* __restrict__ ori,
    const __hip_bfloat16* __restrict__ W2Tb, const float* __restrict__ b2,
    const __hip_bfloat16* __restrict__ SrcRec, const __hip_bfloat16* __restrict__ Qt,
    const __hip_bfloat16* __restrict__ W1cgT,
    float* __restrict__ out) {
    __shared__ int s_srcM[2][64], s_dstM[2][64];
    __shared__ alignas(16) __hip_bfloat16 hVG[64][72];    // [0:32) rot-hv, [32:64) geo
    __shared__ alignas(16) __hip_bfloat16 s_vf[64][104];  // vec+geo contrib / msg
    __shared__ alignas(16) short sW2f[18 * 64 * 8];       // W2 frags, lane-packed
    __shared__ int s_segstart[66];

    const int t = threadIdx.x;
    const int lane = t & 63;
    const int w = t >> 6;        // wave id 0..3
    const int m16 = lane & 15;
    const int q = lane >> 4;
    const int el = t >> 2;       // edge-role: edge index 0..63 (own-wave rows)
    const int quad = t & 3;      // edge-role: quad 0..3
    const int eM = w * 16 + m16; // MFMA-role: A-fragment edge (own-wave row)

    // W2 fragments -> LDS, packed by (frag, lane): ds_read_b128 at lane*16B.
    if (w == 0) {
        for (int f = 0; f < 18; ++f) {
            int nt = f / 3, kt = f - (f / 3) * 3;
            *(s16x8*)&sW2f[(f * 64 + lane) * 8] =
                *(const s16x8*)&W2Tb[(nt * 16 + m16) * 96 + kt * 32 + q * 8];
        }
    }
    // W1cg fragments (K=64 -> 2 per nt) in registers.
    s16x8 bfrC[6][2];
    #pragma unroll
    for (int nt = 0; nt < 6; ++nt)
        #pragma unroll
        for (int kt = 0; kt < 2; ++kt)
            bfrC[nt][kt] = *(const s16x8*)&W1cgT[(nt * 16 + m16) * 64 + kt * 32 + q * 8];
    float b2v[6];
    #pragma unroll
    for (int nt = 0; nt < 6; ++nt) b2v[nt] = b2[nt * 16 + m16];

    // Chunked, XCD-swizzled tile range.
    int b = blockIdx.x;
    int xcd = b & 7, bi = b >> 3;
    int c = (xcd < XR) ? (xcd * (XQ + 1) + bi)
                       : (XR * (XQ + 1) + (xcd - XR) * XQ + bi);
    const int tile0 = c * TPB_E;

    // ---- prologue: stage tile 0 meta, prefetch tile 1's edge ids ----
    int2 edT1;            // edges for tile tl+1 (edge-role)
    s16x8 hvvT;           // raw hv gather for current tile
    float rcT, rsT;       // rotation coeffs (current tile)
    float gdT, gcgT, gsgT;// geo features (current tile)
    {
        int2 edT = edges[tile0 * 64 + el];
        edT1 = edges[(tile0 + 1) * 64 + el];
        hvvT = *(const s16x8*)&SrcRec[edT.x * 128 + 96 + quad * 8];
        int sN = edT.x, dN = edT.y;
        float ca, sa, cb, sb;
        __sincosf(2.0f * ori[dN], &sa, &ca);
        __sincosf(2.0f * ori[sN], &sb, &cb);
        rcT = cb * ca + sb * sa;
        rsT = sb * ca - cb * sa;
        float dx = pos[2 * sN] - pos[2 * dN];
        float dy = pos[2 * sN + 1] - pos[2 * dN + 1];
        float d2 = dx * dx + dy * dy;
        gdT = sqrtf(d2) + 1e-6f;
        float c2f, s2f;
        if (d2 > 0.f) {
            float inv = __builtin_amdgcn_rcpf(d2);
            c2f = (dx * dx - dy * dy) * inv;
            s2f = 2.0f * dx * dy * inv;
        } else { c2f = 1.0f; s2f = 0.0f; }
        gcgT = c2f * ca + s2f * sa;
        gsgT = s2f * ca - c2f * sa;
        if (quad == 0) { s_srcM[0][el] = sN; s_dstM[0][el] = dN; }
    }
    __syncthreads();
    // Issue P/Q gathers for tile 0 (A-frag-aligned: edge eM, chunks kt*32+q*8).
    s16x8 pqP[3], pqQ[3];
    {
        int sN = s_srcM[0][eM], dN = s_dstM[0][eM];
        #pragma unroll
        for (int kt = 0; kt < 3; ++kt) {
            pqP[kt] = *(const s16x8*)&SrcRec[sN * 128 + kt * 32 + q * 8];
            pqQ[kt] = *(const s16x8*)&Qt[dN * 96 + kt * 32 + q * 8];
        }
    }

    int cur = 0;
    for (int tl = 0; tl < TPB_E; ++tl) {
        const int nx = cur ^ 1;
        const int tlN2 = (tl + 2 < TPB_E) ? tl + 2 : TPB_E - 1;

        // 1. rotate hv(T) + geo -> hVG rows (own-wave; in-order LDS)
        {
            s16x8 rv;
            #pragma unroll
            for (int p2 = 0; p2 < 4; ++p2) {
                float x = bfbits2f(hvvT[2 * p2]), y = bfbits2f(hvvT[2 * p2 + 1]);
                rv[2 * p2]     = f2bfbits(rcT * x - rsT * y);
                rv[2 * p2 + 1] = f2bfbits(rsT * x + rcT * y);
            }
            *(s16x8*)&hVG[el][quad * 8] = rv;
            s16x8 up = (s16x8){0, 0, 0, 0, 0, 0, 0, 0};
            if (quad == 0) {
                up[0] = f2bfbits(gdT); up[1] = f2bfbits(gcgT); up[2] = f2bfbits(gsgT);
            }
            *(s16x8*)&hVG[el][32 + quad * 8] = up;
        }
        // 2/3. prefetch edges(T+2) and hv(T+1) — long-latency, used next iter
        int2 edT2 = edges[(tile0 + tlN2) * 64 + el];
        s16x8 hvvN = *(const s16x8*)&SrcRec[edT1.x * 128 + 96 + quad * 8];
        // 4. vec+geo via K=64 MFMA -> s_vf rows (own-wave)
        {
            s16x8 afr0 = *(const s16x8*)&hVG[eM][q * 8];
            s16x8 afr1 = *(const s16x8*)&hVG[eM][32 + q * 8];
            #pragma unroll
            for (int nt = 0; nt < 6; ++nt) {
                f32x4 a1 = __builtin_amdgcn_mfma_f32_16x16x32_bf16(
                    afr0, bfrC[nt][0], (f32x4){0.f, 0.f, 0.f, 0.f}, 0, 0, 0);
                a1 = __builtin_amdgcn_mfma_f32_16x16x32_bf16(
                    afr1, bfrC[nt][1], a1, 0, 0, 0);
                int u = nt * 16 + m16;
                #pragma unroll
                for (int r = 0; r < 4; ++r)
                    s_vf[w * 16 + q * 4 + r][u] = f2bf(a1[r]);
            }
        }
        // 5. meta + rotation + geo for T+1 -> regs + meta[nx] (own-wave rows)
        float rcN, rsN, gdN, gcgN, gsgN;
        {
            int sN = edT1.x, dN = edT1.y;
            float ca, sa, cb, sb;
            __sincosf(2.0f * ori[dN], &sa, &ca);
            __sincosf(2.0f * ori[sN], &sb, &cb);
            rcN = cb * ca + sb * sa;
            rsN = sb * ca - cb * sa;
            float dx = pos[2 * sN] - pos[2 * dN];
            float dy = pos[2 * sN + 1] - pos[2 * dN + 1];
            float d2 = dx * dx + dy * dy;
            gdN = sqrtf(d2) + 1e-6f;
            float c2f, s2f;
            if (d2 > 0.f) {
                float inv = __builtin_amdgcn_rcpf(d2);
                c2f = (dx * dx - dy * dy) * inv;
                s2f = 2.0f * dx * dy * inv;
            } else { c2f = 1.0f; s2f = 0.0f; }
            gcgN = c2f * ca + s2f * sa;
            gsgN = s2f * ca - c2f * sa;
            if (quad == 0) { s_srcM[nx][el] = sN; s_dstM[nx][el] = dN; }
        }

        // 6. phase-1b: silu(P + Q + V) straight into A-fragments (no barrier:
        //    s_vf rows w*16..w*16+15 were written by this wave in step 4)
        s16x8 afr[3];
        #pragma unroll
        for (int kt = 0; kt < 3; ++kt) {
            int j = kt * 32 + q * 8;
            s16x8 Vv = *(const s16x8*)&s_vf[eM][j];
            s16x8 hb;
            #pragma unroll
            for (int k2 = 0; k2 < 8; ++k2) {
                float pre = bfbits2f(pqP[kt][k2]) + bfbits2f(pqQ[kt][k2])
                          + bfbits2f(Vv[k2]);
                float h = pre * __builtin_amdgcn_rcpf(1.0f + __expf(-pre));  // silu
                hb[k2] = f2bfbits(h);
            }
            afr[kt] = hb;
        }
        // 7. prefetch P/Q for T+1 (meta[nx] written by own wave in step 5)
        {
            int sN = s_srcM[nx][eM], dN = s_dstM[nx][eM];
            #pragma unroll
            for (int kt = 0; kt < 3; ++kt) {
                pqP[kt] = *(const s16x8*)&SrcRec[sN * 128 + kt * 32 + q * 8];
                pqQ[kt] = *(const s16x8*)&Qt[dN * 96 + kt * 32 + q * 8];
            }
        }
        // 8. layer-2 MFMA (B frags from LDS) -> msg overwrites s_vf (own-wave;
        //    LDS in-order guarantees step-6 reads complete first)
        {
            f32x4 acc[6];
            #pragma unroll
            for (int nt = 0; nt < 6; ++nt) acc[nt] = (f32x4){0.f, 0.f, 0.f, 0.f};
            #pragma unroll
            for (int nt = 0; nt < 6; ++nt)
                #pragma unroll
                for (int kt = 0; kt < 3; ++kt) {
                    s16x8 bf = *(const s16x8*)&sW2f[((nt * 3 + kt) * 64 + lane) * 8];
                    acc[nt] = __builtin_amdgcn_mfma_f32_16x16x32_bf16(
                        afr[kt], bf, acc[nt], 0, 0, 0);
                }
            #pragma unroll
            for (int nt = 0; nt < 6; ++nt) {
                int u = nt * 16 + m16;
                float bb = b2v[nt];
                #pragma unroll
                for (int r = 0; r < 4; ++r)
                    s_vf[w * 16 + q * 4 + r][u] = f2bf(acc[nt][r] + bb);
            }
        }
        __syncthreads();  // [B1] all waves' msg + meta visible

        // 9. segment ballot (redundant per wave) + reduce, one atomic per
        //    (segment, unit)
        {
            int dl = s_dstM[cur][lane];
            int dp = (lane > 0) ? s_dstM[cur][lane - 1] : -1;
            bool bnd = (lane > 0) && (dl != dp);
            unsigned long long mask = __ballot(bnd);
            int nseg = (int)__popcll(mask) + 1;
            if (bnd) s_segstart[__popcll(mask & (~0ull >> (63 - lane)))] = lane;
            if (lane == 0) s_segstart[0] = 0;

            for (int idx = t; idx < nseg * HID; idx += 256) {
                int sg = idx / HID;
                int u = idx - sg * HID;
                int e0 = s_segstart[sg];
                int e1 = (sg + 1 < nseg) ? s_segstart[sg + 1] : 64;
                float sum = 0.f;
                for (int e = e0; e < e1; ++e) sum += bf2f(s_vf[e][u]);
                int dN = s_dstM[cur][e0];
                if (u < SDIM) atomicAdd(&out[dN * SDIM + u], sum);
                else atomicAdd(&out[N_NODESC * SDIM + dN * VDIM + (u - SDIM)], sum);
            }
        }

        // 10. rotate pipeline state
        edT1 = edT2; hvvT = hvvN;
        rcT = rcN; rsT = rsN; gdT = gdN; gcgT = gcgN; gsgT = gsgN;
        cur = nx;
        __syncthreads();  // [B2] reduce done before next tile overwrites LDS
    }
}

// ---------------------------------------------------------------------------
// Mid-tier: f32 per-node precompute (4 tables) + unsorted atomic-scatter kernel.
__global__ __launch_bounds__(128) void node_precompute(
    const float* __restrict__ hs, const float* __restrict__ hv,
    const float* __restrict__ W1, const float* __restrict__ b1,
    __hip_bfloat16* __restrict__ Pp, __hip_bfloat16* __restrict__ Qt,
    __hip_bfloat16* __restrict__ Ut, __hip_bfloat16* __restrict__ Vt) {
    int n = blockIdx.x;
    __shared__ float s_hs[SDIM];
    __shared__ float s_hv[VDIM];
    int t = threadIdx.x;
    if (t < 64) s_hs[t] = hs[n * SDIM + t];
    else if (t < 96) s_hv[t - 64] = hv[n * VDIM + (t - 64)];
    __syncthreads();
    if (t < HID) {
        float p = b1[t], qq = 0.f, u = 0.f, v = 0.f;
        for (int k = 0; k < 64; ++k) {
            float x = s_hs[k];
            p += x * W1[k * HID + t];
            qq += x * W1[(64 + k) * HID + t];
        }
        for (int pr = 0; pr < 16; ++pr) {
            float x = s_hv[2 * pr], y = s_hv[2 * pr + 1];
            float wa = W1[(128 + 2 * pr) * HID + t];
            float wb = W1[(128 + 2 * pr + 1) * HID + t];
            u += x * wa + y * wb;
            v += x * wb - y * wa;
        }
        Pp[n * HID + t] = f2bf(p);
        Qt[n * HID + t] = f2bf(qq);
        Ut[n * HID + t] = f2bf(u);
        Vt[n * HID + t] = f2bf(v);
    }
}

__global__ void init_out(const float* __restrict__ hs, const float* __restrict__ hv,
                         float* __restrict__ out) {
    int i = blockIdx.x * blockDim.x + threadIdx.x;
    if (i >= N_NODESC * (SDIM + VDIM)) return;
    out[i] = (i < N_NODESC * SDIM) ? hs[i] : hv[i - N_NODESC * SDIM];
}

__global__ void detect_kernel(const int* ei, int* flag) {
    if (blockIdx.x == 0 && threadIdx.x == 0) {
        int z = 1;
        for (int k = 0; k < 64; ++k) {
            if (ei[2 * k + 1] != 0) { z = 0; break; }
        }
        *flag = z;
    }
}

__global__ __launch_bounds__(256) void edge_kernel(
    const int* __restrict__ ei, const float* __restrict__ pos,
    const float* __restrict__ ori, const float* __restrict__ W1,
    const float* __restrict__ W2, const float* __restrict__ b2,
    const __hip_bfloat16* __restrict__ Pp, const __hip_bfloat16* __restrict__ Qt,
    const __hip_bfloat16* __restrict__ Ut, const __hip_bfloat16* __restrict__ Vt,
    const int* __restrict__ flag64, float* __restrict__ out) {
    __shared__ int s_src[64], s_dst[64];
    __shared__ float s_c[64], s_s[64], s_d[64], s_cg[64], s_sg[64];
    __shared__ float s_w1d[3][HID];
    __shared__ __hip_bfloat16 hA[64][104];
    __shared__ __hip_bfloat16 W2T[HID][104];

    const int t = threadIdx.x;
    const int lane = t & 63;
    const int w = t >> 6;
    const int m16 = lane & 15;
    const int q = lane >> 4;

    for (int idx = t; idx < HID * HID; idx += 256) {
        int k = idx / HID;
        int n = idx - k * HID;
        W2T[n][k] = f2bf(W2[idx]);
    }
    for (int idx = t; idx < 3 * HID; idx += 256) {
        int r = idx / HID, j = idx - r * HID;
        s_w1d[r][j] = W1[(160 + r) * HID + j];
    }
    __syncthreads();

    s16x8 bfr[6][3];
    for (int nt = 0; nt < 6; ++nt)
        for (int kt = 0; kt < 3; ++kt)
            bfr[nt][kt] = *(const s16x8*)&W2T[nt * 16 + m16][kt * 32 + q * 8];
    float b2v[6];
    for (int nt = 0; nt < 6; ++nt) b2v[nt] = b2[nt * 16 + m16];

    const bool i64 = (*flag64 != 0);
    const long long* ei64 = (const long long*)ei;

    for (int tile = blockIdx.x; tile < N_EDGESC / 64; tile += gridDim.x) {
        __syncthreads();

        if (t < 64) {
            int e = tile * 64 + t;
            int sN, dN;
            if (i64) { sN = (int)ei64[e]; dN = (int)ei64[N_EDGESC + e]; }
            else     { sN = ei[e];        dN = ei[N_EDGESC + e]; }
            s_src[t] = sN; s_dst[t] = dN;
            float ca, sa, cb, sb;
            __sincosf(2.0f * ori[dN], &sa, &ca);
            __sincosf(2.0f * ori[sN], &sb, &cb);
            s_c[t] = cb * ca + sb * sa;
            s_s[t] = sb * ca - cb * sa;
            float dx = pos[2 * sN] - pos[2 * dN];
            float dy = pos[2 * sN + 1] - pos[2 * dN + 1];
            float d2 = dx * dx + dy * dy;
            s_d[t] = sqrtf(d2) + 1e-6f;
            float c2f, s2f;
            if (d2 > 0.f) {
                float inv = 1.0f / d2;
                c2f = (dx * dx - dy * dy) * inv;
                s2f = 2.0f * dx * dy * inv;
            } else { c2f = 1.0f; s2f = 0.0f; }
            s_cg[t] = c2f * ca + s2f * sa;
            s_sg[t] = s2f * ca - c2f * sa;
        }
        __syncthreads();

        for (int p = 0; p < 24; ++p) {
            int idx = p * 256 + t;
            int e = idx / HID;
            int j = idx - e * HID;
            int sN = s_src[e], dN = s_dst[e];
            float pre = bf2f(Pp[sN * HID + j]) + bf2f(Qt[dN * HID + j])
                      + s_c[e] * bf2f(Ut[sN * HID + j])
                      + s_s[e] * bf2f(Vt[sN * HID + j])
                      + s_d[e] * s_w1d[0][j] + s_cg[e] * s_w1d[1][j]
                      + s_sg[e] * s_w1d[2][j];
            float h = pre / (1.0f + __expf(-pre));
            hA[e][j] = f2bf(h);
        }
        __syncthreads();

        f32x4 acc[6];
        for (int nt = 0; nt < 6; ++nt) acc[nt] = (f32x4){0.f, 0.f, 0.f, 0.f};
        s16x8 afr[3];
        for (int kt = 0; kt < 3; ++kt)
            afr[kt] = *(const s16x8*)&hA[w * 16 + m16][kt * 32 + q * 8];
        for (int nt = 0; nt < 6; ++nt)
            for (int kt = 0; kt < 3; ++kt)
                acc[nt] = __builtin_amdgcn_mfma_f32_16x16x32_bf16(
                    afr[kt], bfr[nt][kt], acc[nt], 0, 0, 0);

        for (int nt = 0; nt < 6; ++nt) {
            int u = nt * 16 + m16;
            for (int r = 0; r < 4; ++r) {
                int eloc = w * 16 + q * 4 + r;
                int dN = s_dst[eloc];
                float val = acc[nt][r] + b2v[nt];
                if (u < SDIM) atomicAdd(&out[dN * SDIM + u], val);
                else atomicAdd(&out[N_NODESC * SDIM + dN * VDIM + (u - SDIM)], val);
            }
        }
    }
}

// ---------------------------------------------------------------------------
// Fallback (ws too small for tables): fully per-edge, correct but slow.
__global__ __launch_bounds__(192) void edge_fallback(
    const int* __restrict__ ei, const float* __restrict__ hs,
    const float* __restrict__ hv, const float* __restrict__ pos,
    const float* __restrict__ ori, const float* __restrict__ W1,
    const float* __restrict__ b1, const float* __restrict__ W2,
    const float* __restrict__ b2, const int* __restrict__ flag64,
    float* __restrict__ out) {
    __shared__ float s_msg[IN_DIMC];
    __shared__ float s_h[HID];
    int e = blockIdx.x;
    int t = threadIdx.x;
    const bool i64 = (*flag64 != 0);
    int sN, dN;
    if (i64) {
        const long long* e64 = (const long long*)ei;
        sN = (int)e64[e]; dN = (int)e64[N_EDGESC + e];
    } else { sN = ei[e]; dN = ei[N_EDGESC + e]; }

    if (t < IN_DIMC) {
        if (t < 64) s_msg[t] = hs[sN * SDIM + t];
        else if (t < 128) s_msg[t] = hs[dN * SDIM + (t - 64)];
        else {
            float ca, sa, cb, sb;
            __sincosf(2.0f * ori[dN], &sa, &ca);
            __sincosf(2.0f * ori[sN], &sb, &cb);
            float c = cb * ca + sb * sa;
            float s = sb * ca - cb * sa;
            float dx = pos[2 * sN] - pos[2 * dN];
            float dy = pos[2 * sN + 1] - pos[2 * dN + 1];
            float d2 = dx * dx + dy * dy;
            if (t < 160) {
                int pr = (t - 128) >> 1;
                float x = hv[sN * VDIM + 2 * pr], y = hv[sN * VDIM + 2 * pr + 1];
                s_msg[t] = ((t & 1) == 0) ? (c * x - s * y) : (s * x + c * y);
            } else if (t == 160) s_msg[t] = sqrtf(d2) + 1e-6f;
            else {
                float c2f = 1.0f, s2f = 0.0f;
                if (d2 > 0.f) {
                    float inv = 1.0f / d2;
                    c2f = (dx * dx - dy * dy) * inv;
                    s2f = 2.0f * dx * dy * inv;
                }
                s_msg[t] = (t == 161) ? (c2f * ca + s2f * sa) : (s2f * ca - c2f * sa);
            }
        }
    }
    __syncthreads();
    if (t < HID) {
        float a = b1[t];
        for (int k = 0; k < IN_DIMC; ++k) a += s_msg[k] * W1[k * HID + t];
        s_h[t] = a / (1.0f + __expf(-a));
    }
    __syncthreads();
    if (t < HID) {
        float a = b2[t];
        for (int k = 0; k < HID; ++k) a += s_h[k] * W2[k * HID + t];
        if (t < SDIM) atomicAdd(&out[dN * SDIM + t], a);
        else atomicAdd(&out[N_NODESC * SDIM + dN * VDIM + (t - SDIM)], a);
    }
}

// ---------------------------------------------------------------------------
extern "C" void kernel_launch(void* const* d_in, const int* in_sizes, int n_in,
                              void* d_out, int out_size, void* d_ws, size_t ws_size,
                              hipStream_t stream) {
    const float* hs  = (const float*)d_in[0];
    const float* hv  = (const float*)d_in[1];
    const int*   ei  = (const int*)d_in[2];
    const float* pos = (const float*)d_in[3];
    const float* ori = (const float*)d_in[4];
    const float* W1  = (const float*)d_in[5];
    const float* b1  = (const float*)d_in[6];
    const float* W2  = (const float*)d_in[7];
    const float* b2  = (const float*)d_in[8];
    float* out = (float*)d_out;

    // sorted-tier workspace layout (256B-aligned chunks)
    const size_t SREC = (size_t)N_NODESC * 128 * sizeof(__hip_bfloat16);  // 12.8 MB
    const size_t QTB  = (size_t)N_NODESC * 96 * sizeof(__hip_bfloat16);   // 9.6 MB
    const size_t CNT  = ((size_t)N_NODESC * sizeof(int) + 255) & ~255ull; // 200 KB
    const size_t EDG  = (size_t)N_EDGESC * sizeof(int2);                  // 12.8 MB
    const size_t WBT2 = ((size_t)192 * 64 * 2 + 255) & ~255ull;
    const size_t W1CG = ((size_t)96 * 64 * 2 + 255) & ~255ull;
    const size_t W2TS = ((size_t)96 * 96 * 2 + 255) & ~255ull;
    const size_t FLG  = 256;
    const size_t BSM  = 1024;  // bsum[196] padded
    const size_t BOF  = 1024;  // boff[196] padded
    const size_t SORT_WS = SREC + QTB + 2 * CNT + EDG + WBT2 + W1CG + W2TS
                         + FLG + BSM + BOF;

    const size_t TBL = (size_t)N_NODESC * HID * sizeof(__hip_bfloat16);   // 9.6 MB
    const bool big = ws_size >= 4 * TBL + 16;
    const bool srt = ws_size >= SORT_WS;

    if (srt) {
        char* ws = (char*)d_ws;
        __hip_bfloat16* SrcRec = (__hip_bfloat16*)(ws);
        __hip_bfloat16* Qt     = (__hip_bfloat16*)(ws + SREC);
        int* counts            = (int*)(ws + SREC + QTB);
        int* cur               = (int*)(ws + SREC + QTB + CNT);
        int2* edges            = (int2*)(ws + SREC + QTB + 2 * CNT);
        __hip_bfloat16* WbT2   = (__hip_bfloat16*)(ws + SREC + QTB + 2 * CNT + EDG);
        __hip_bfloat16* W1cgT  = (__hip_bfloat16*)(ws + SREC + QTB + 2 * CNT + EDG + WBT2);
        __hip_bfloat16* W2Tb   = (__hip_bfloat16*)(ws + SREC + QTB + 2 * CNT + EDG + WBT2 + W1CG);
        char* tail             = ws + SREC + QTB + 2 * CNT + EDG + WBT2 + W1CG + W2TS;
        int* flag              = (int*)(tail);
        int* bsum              = (int*)(tail + FLG);
        int* boff              = (int*)(tail + FLG + BSM);

        detect_zero<<<(N_NODESC + 255) / 256, 256, 0, stream>>>(ei, flag, counts);
        fused_init<<<N_EDGESC / 256, 256, 0, stream>>>(
            hs, hv, out, counts, W1, W2, SrcRec, WbT2, W1cgT, W2Tb, ei, flag);
        scan_partials<<<SCB, 256, 0, stream>>>(counts, cur, bsum);
        scan_bsums<<<1, 256, 0, stream>>>(bsum, boff);
        scan_apply<<<SCB, 256, 0, stream>>>(cur, boff);
        scatter_precompute<<<NPRE + N_EDGESC / 256, 256, 0, stream>>>(
            ei, flag, cur, edges, hs, WbT2, b1, SrcRec, Qt);
        edge_kernel_sorted<<<GRID_E, 256, 0, stream>>>(edges, pos, ori, W2Tb, b2,
                                                       SrcRec, Qt, W1cgT, out);
    } else if (big) {
        char* ws = (char*)d_ws;
        __hip_bfloat16* Pp = (__hip_bfloat16*)(ws);
        __hip_bfloat16* Qt = (__hip_bfloat16*)(ws + TBL);
        __hip_bfloat16* Ut = (__hip_bfloat16*)(ws + 2 * TBL);
        __hip_bfloat16* Vt = (__hip_bfloat16*)(ws + 3 * TBL);
        int* flag = (int*)(ws + 4 * TBL);
        init_out<<<(N_NODESC * (SDIM + VDIM) + 255) / 256, 256, 0, stream>>>(hs, hv, out);
        detect_kernel<<<1, 64, 0, stream>>>(ei, flag);
        node_precompute<<<N_NODESC, 128, 0, stream>>>(hs, hv, W1, b1, Pp, Qt, Ut, Vt);
        edge_kernel<<<2500, 256, 0, stream>>>(ei, pos, ori, W1, W2, b2,
                                              Pp, Qt, Ut, Vt, flag, out);
    } else {
        int* flag = (int*)d_ws;
        init_out<<<(N_NODESC * (SDIM + VDIM) + 255) / 256, 256, 0, stream>>>(hs, hv, out);
        detect_kernel<<<1, 64, 0, stream>>>(ei, flag);
        edge_fallback<<<N_EDGESC, 192, 0, stream>>>(ei, hs, hv, pos, ori, W1, b1,
                                                    W2, b2, flag, out);
    }
}